// Round 4
// baseline (516.049 us; speedup 1.0000x reference)
//
#include <hip/hip_runtime.h>
#include <hip/hip_bf16.h>
#include <stdint.h>

#define NN 50000
#define NE 600000
#define IN_DIM 512
#define HID 128
#define ODIM 64
#define EPSV 0.1f
#define NBLK ((NN + 255) / 256)  // 196 scan blocks

typedef __attribute__((ext_vector_type(8))) short short8;
typedef __attribute__((ext_vector_type(4))) float f32x4;

__device__ __forceinline__ ushort f2bf(float f) {
    union { float f; uint32_t i; } v; v.f = f;
    uint32_t lsb = (v.i >> 16) & 1u;
    uint32_t r = v.i + 0x7fffu + lsb;
    return (ushort)(r >> 16);
}

__device__ __forceinline__ short8 pack8v(f32x4 lo, f32x4 hi) {
    short8 r;
    r[0] = (short)f2bf(lo[0]); r[1] = (short)f2bf(lo[1]);
    r[2] = (short)f2bf(lo[2]); r[3] = (short)f2bf(lo[3]);
    r[4] = (short)f2bf(hi[0]); r[5] = (short)f2bf(hi[1]);
    r[6] = (short)f2bf(hi[2]); r[7] = (short)f2bf(hi[3]);
    return r;
}

// fast tanh: (e^2z - 1) / (e^2z + 1), clamped
__device__ __forceinline__ float fast_tanh(float z) {
    z = fminf(fmaxf(z, -15.f), 15.f);
    float t = __expf(2.f * z);
    return __fdividef(t - 1.f, t + 1.f);
}

// ---- degree count ----
__global__ __launch_bounds__(256) void deg_kernel(const int* __restrict__ dst, int* __restrict__ deg) {
    int e = blockIdx.x * 256 + threadIdx.x;
    if (e < NE) atomicAdd(&deg[dst[e]], 1);
}

// ---- scan phase A ----
__global__ __launch_bounds__(256) void scanA_kernel(const int* __restrict__ deg,
                                                    int* __restrict__ localScan,
                                                    int* __restrict__ blockSums,
                                                    float* __restrict__ dinv) {
    __shared__ int tmp[256];
    int t = threadIdx.x;
    int i = blockIdx.x * 256 + t;
    int v = (i < NN) ? deg[i] : 0;
    tmp[t] = v;
    __syncthreads();
    for (int off = 1; off < 256; off <<= 1) {
        int add = (t >= off) ? tmp[t - off] : 0;
        __syncthreads();
        tmp[t] += add;
        __syncthreads();
    }
    if (i < NN) {
        localScan[i] = tmp[t] - v;
        dinv[i] = (v > 0) ? (1.0f / sqrtf((float)v)) : 0.0f;
    }
    if (t == 255) blockSums[blockIdx.x] = tmp[255];
}

// ---- scan phase B ----
__global__ __launch_bounds__(256) void scanB_kernel(const int* __restrict__ blockSums,
                                                    int* __restrict__ blockOff) {
    __shared__ int tmp[256];
    int t = threadIdx.x;
    int v = (t < NBLK) ? blockSums[t] : 0;
    tmp[t] = v;
    __syncthreads();
    for (int off = 1; off < 256; off <<= 1) {
        int add = (t >= off) ? tmp[t - off] : 0;
        __syncthreads();
        tmp[t] += add;
        __syncthreads();
    }
    blockOff[t] = tmp[t] - v;
}

// ---- scan phase C ----
__global__ __launch_bounds__(256) void scanC_kernel(const int* __restrict__ localScan,
                                                    const int* __restrict__ blockOff,
                                                    int* __restrict__ rowptr,
                                                    int* __restrict__ cursor) {
    int i = blockIdx.x * 256 + threadIdx.x;
    if (i < NN) {
        int v = localScan[i] + blockOff[blockIdx.x];
        rowptr[i] = v;
        cursor[i] = v;
    }
    if (i == 0) rowptr[NN] = NE;
}

// ---- fill CSR ----
__global__ __launch_bounds__(256) void fill_kernel(const int* __restrict__ src, const int* __restrict__ dst,
                                                   int* __restrict__ cursor, int* __restrict__ csr_src) {
    int e = blockIdx.x * 256 + threadIdx.x;
    if (e < NE) {
        int d = dst[e];
        int slot = atomicAdd(&cursor[d], 1);
        csr_src[slot] = src[e];
    }
}

// ---- convert W1 fp32 -> bf16 ----
__global__ __launch_bounds__(256) void cvtw_kernel(const float* __restrict__ w, ushort* __restrict__ wbf) {
    int i = blockIdx.x * 256 + threadIdx.x;
    if (i < HID * IN_DIM) wbf[i] = f2bf(w[i]);
}

// ---- h0 = relu(x @ W1^T + b1), fused layer-0 attention scalars ----
// v4: ONE-SHOT tile staging. Diagnosis: v0/v2/v3 all pinned at ~0.9 TB/s
// because each K-step's HBM work drained within that K-step (in-order vmcnt
// entanglement / per-step vmcnt(0)+barrier) -> ~700cy exposed latency per
// step per wave. Fix: stage the block's ENTIRE 64x512 f32 x-tile (128 KB
// LDS) in one burst of 32 back-to-back global_load_lds per wave (32 KB in
// flight per wave), ONE vmcnt(0)+barrier, then pure compute: A from LDS,
// B from L2-resident wbf, zero HBM dependency in the MFMA loop. Load phase
// is a contiguous tiled memcpy -> memcpy-class BW. Granule XOR-swizzle via
// pre-swizzled GLOBAL source (rule #21): LDS[row][w] = x[row][w ^ ((row&7)<<2)]
// (4-word granules) so fragment f32x4 reads are ~conflict-free.
__global__ __launch_bounds__(256) void gemm1_kernel(const float* __restrict__ x,
                                                    const ushort* __restrict__ wbf,
                                                    const float* __restrict__ b,
                                                    const float* __restrict__ attl,
                                                    const float* __restrict__ attr,
                                                    const float* __restrict__ dinv,
                                                    float* __restrict__ h,
                                                    float2* __restrict__ AD,
                                                    float* __restrict__ AR) {
    __shared__ __attribute__((aligned(16))) float a_sm[64 * 512]; // 128 KB
    int t = threadIdx.x;
    int wv = __builtin_amdgcn_readfirstlane(t >> 6);
    int lane = t & 63;
    int m0 = blockIdx.x * 64;

    // ---- stage whole tile: 32 rounds x (4 waves x 1KB) ----
    // round j: wave wv covers LDS floats [j*1024 + wv*256, +256)
    // row = 2j + (wv>>1) (wave-uniform), w = (wv&1)*256 + lane*4
    {
        int w0 = (wv & 1) * 256 + lane * 4;
#pragma unroll
        for (int j = 0; j < 32; ++j) {
            int row = 2 * j + (wv >> 1);
            int grow = m0 + row; if (grow >= NN) grow = NN - 1;
            int col = w0 ^ ((row & 7) << 2);
            const float* g = x + (size_t)grow * IN_DIM + col;
            __builtin_amdgcn_global_load_lds(g, &a_sm[j * 1024 + (wv & 1) * 256 + (wv >> 1) * 512], 16, 0, 0);
        }
    }

    // fragment map
    int rsel = lane & 15;
    int koff = (lane >> 4) * 8;
    int sw2 = (rsel & 7) << 2;             // row-swizzle key (words)
    int rloc = wv * 16 + rsel;             // tile row this lane consumes
    const ushort* wp0 = wbf + (size_t)rsel * IN_DIM + koff;

    f32x4 acc[8];
#pragma unroll
    for (int tt = 0; tt < 8; ++tt) acc[tt] = (f32x4){0.f, 0.f, 0.f, 0.f};

    asm volatile("s_waitcnt vmcnt(0)");
    __syncthreads();

    // ---- pure-compute K loop: 16 sub-steps x 8 MFMA, no HBM deps ----
#pragma unroll
    for (int s = 0; s < 16; ++s) {
        int W0 = (s * 32 + koff) ^ sw2;
        f32x4 f0 = *(const f32x4*)&a_sm[rloc * 512 + W0];
        f32x4 f1 = *(const f32x4*)&a_sm[rloc * 512 + (W0 ^ 4)];
        short8 a = pack8v(f0, f1);
#pragma unroll
        for (int tt = 0; tt < 8; ++tt) {
            short8 bf = *(const short8*)(wp0 + (size_t)tt * 16 * IN_DIM + s * 32);
            acc[tt] = __builtin_amdgcn_mfma_f32_16x16x32_bf16(a, bf, acc[tt], 0, 0, 0);
        }
    }

    // epilogue: bias + relu + store + fused layer-0 attention scalars
    int rbase = (lane >> 4) * 4;
    int col0 = lane & 15;
    float alv[8], arv[8], bias[8];
#pragma unroll
    for (int tt = 0; tt < 8; ++tt) {
        alv[tt]  = attl[tt * 16 + col0];
        arv[tt]  = attr[tt * 16 + col0];
        bias[tt] = b[tt * 16 + col0];
    }
#pragma unroll
    for (int r = 0; r < 4; ++r) {
        int rrow = m0 + wv * 16 + rbase + r;
        float p = 0.f, q = 0.f;
#pragma unroll
        for (int tt = 0; tt < 8; ++tt) {
            float v = acc[tt][r] + bias[tt];
            v = v > 0.f ? v : 0.f;
            if (rrow < NN) h[(size_t)rrow * HID + tt * 16 + col0] = v;
            p += v * alv[tt];
            q += v * arv[tt];
        }
#pragma unroll
        for (int off = 8; off; off >>= 1) { p += __shfl_xor(p, off); q += __shfl_xor(q, off); }
        if (col0 == 0 && rrow < NN) {
            float2 vv; vv.x = p; vv.y = dinv[rrow];
            AD[rrow] = vv;
            AR[rrow] = q;
        }
    }
}

// ---- FAConv aggregation: wave per dst node, 8-deep edge unroll for MLP ----
__global__ __launch_bounds__(256) void agg_kernel(const float* __restrict__ h,
                                                  const float* __restrict__ raw,
                                                  float* __restrict__ hn,
                                                  const int* __restrict__ rowptr,
                                                  const int* __restrict__ csr_src,
                                                  const float* __restrict__ dinv,
                                                  const float2* __restrict__ AD,
                                                  const float* __restrict__ AR,
                                                  const float* __restrict__ attl_next,
                                                  const float* __restrict__ attr_next,
                                                  float2* __restrict__ ADout,
                                                  float* __restrict__ ARout) {
    int wv = __builtin_amdgcn_readfirstlane(threadIdx.x >> 6);
    int lane = threadIdx.x & 63;
    int d = blockIdx.x * 4 + wv;
    if (d >= NN) return;
    const float2* h2 = (const float2*)h;
    float ar_d = AR[d];
    float dinv_d = dinv[d];
    float2 rawd = ((const float2*)raw)[(size_t)d * 64 + lane];
    float accx = EPSV * rawd.x, accy = EPSV * rawd.y;
    int e = rowptr[d], e1 = rowptr[d + 1];
    // ---- 8-deep: 1 broadcast index load + 8 concurrent 512B row loads ----
    for (; e + 8 <= e1; e += 8) {
        int sv = csr_src[e + (lane & 7)];
        int s0 = __builtin_amdgcn_readfirstlane(__shfl(sv, 0));
        int s1 = __builtin_amdgcn_readfirstlane(__shfl(sv, 1));
        int s2 = __builtin_amdgcn_readfirstlane(__shfl(sv, 2));
        int s3 = __builtin_amdgcn_readfirstlane(__shfl(sv, 3));
        int s4 = __builtin_amdgcn_readfirstlane(__shfl(sv, 4));
        int s5 = __builtin_amdgcn_readfirstlane(__shfl(sv, 5));
        int s6 = __builtin_amdgcn_readfirstlane(__shfl(sv, 6));
        int s7 = __builtin_amdgcn_readfirstlane(__shfl(sv, 7));
        float2 ad0 = AD[s0], ad1 = AD[s1], ad2 = AD[s2], ad3 = AD[s3];
        float2 ad4 = AD[s4], ad5 = AD[s5], ad6 = AD[s6], ad7 = AD[s7];
        float2 v0 = h2[(size_t)s0 * 64 + lane];
        float2 v1 = h2[(size_t)s1 * 64 + lane];
        float2 v2 = h2[(size_t)s2 * 64 + lane];
        float2 v3 = h2[(size_t)s3 * 64 + lane];
        float2 v4 = h2[(size_t)s4 * 64 + lane];
        float2 v5 = h2[(size_t)s5 * 64 + lane];
        float2 v6 = h2[(size_t)s6 * 64 + lane];
        float2 v7 = h2[(size_t)s7 * 64 + lane];
        float w0 = fast_tanh(ad0.x + ar_d) * ad0.y * dinv_d;
        float w1 = fast_tanh(ad1.x + ar_d) * ad1.y * dinv_d;
        float w2 = fast_tanh(ad2.x + ar_d) * ad2.y * dinv_d;
        float w3 = fast_tanh(ad3.x + ar_d) * ad3.y * dinv_d;
        float w4 = fast_tanh(ad4.x + ar_d) * ad4.y * dinv_d;
        float w5 = fast_tanh(ad5.x + ar_d) * ad5.y * dinv_d;
        float w6 = fast_tanh(ad6.x + ar_d) * ad6.y * dinv_d;
        float w7 = fast_tanh(ad7.x + ar_d) * ad7.y * dinv_d;
        accx += w0 * v0.x + w1 * v1.x + w2 * v2.x + w3 * v3.x;
        accy += w0 * v0.y + w1 * v1.y + w2 * v2.y + w3 * v3.y;
        accx += w4 * v4.x + w5 * v5.x + w6 * v6.x + w7 * v7.x;
        accy += w4 * v4.y + w5 * v5.y + w6 * v6.y + w7 * v7.y;
    }
    for (; e + 4 <= e1; e += 4) {
        int sv = csr_src[e + (lane & 3)];
        int s0 = __builtin_amdgcn_readfirstlane(__shfl(sv, 0));
        int s1 = __builtin_amdgcn_readfirstlane(__shfl(sv, 1));
        int s2 = __builtin_amdgcn_readfirstlane(__shfl(sv, 2));
        int s3 = __builtin_amdgcn_readfirstlane(__shfl(sv, 3));
        float2 ad0 = AD[s0], ad1 = AD[s1], ad2 = AD[s2], ad3 = AD[s3];
        float2 v0 = h2[(size_t)s0 * 64 + lane];
        float2 v1 = h2[(size_t)s1 * 64 + lane];
        float2 v2 = h2[(size_t)s2 * 64 + lane];
        float2 v3 = h2[(size_t)s3 * 64 + lane];
        float w0 = fast_tanh(ad0.x + ar_d) * ad0.y * dinv_d;
        float w1 = fast_tanh(ad1.x + ar_d) * ad1.y * dinv_d;
        float w2 = fast_tanh(ad2.x + ar_d) * ad2.y * dinv_d;
        float w3 = fast_tanh(ad3.x + ar_d) * ad3.y * dinv_d;
        accx += w0 * v0.x + w1 * v1.x + w2 * v2.x + w3 * v3.x;
        accy += w0 * v0.y + w1 * v1.y + w2 * v2.y + w3 * v3.y;
    }
    for (; e < e1; ++e) {
        int s = __builtin_amdgcn_readfirstlane(csr_src[e]);
        float2 ad = AD[s];
        float2 v = h2[(size_t)s * 64 + lane];
        float w = fast_tanh(ad.x + ar_d) * ad.y * dinv_d;
        accx += w * v.x;
        accy += w * v.y;
    }
    float2 o; o.x = accx; o.y = accy;
    ((float2*)hn)[(size_t)d * 64 + lane] = o;
    if (attl_next) {
        float al0 = attl_next[2 * lane], al1 = attl_next[2 * lane + 1];
        float ar0 = attr_next[2 * lane], ar1 = attr_next[2 * lane + 1];
        float p = accx * al0 + accy * al1;
        float q = accx * ar0 + accy * ar1;
#pragma unroll
        for (int off = 32; off; off >>= 1) { p += __shfl_xor(p, off); q += __shfl_xor(q, off); }
        if (lane == 0) {
            float2 v; v.x = p; v.y = dinv_d;
            ADout[d] = v;
            ARout[d] = q;
        }
    }
}

// ---- head: emb = h @ W2^T + b2; out0 = log_softmax(emb); out1 = emb ----
__global__ __launch_bounds__(256) void head_kernel(const float* __restrict__ h,
                                                   const float* __restrict__ w2,
                                                   const float* __restrict__ b2,
                                                   float* __restrict__ out) {
    __shared__ float w2t[HID * 65];
    int t = threadIdx.x;
    for (int i = t; i < HID * ODIM; i += 256) {
        int j = i >> 7, k = i & 127;
        w2t[k * 65 + j] = w2[i];
    }
    __syncthreads();
    int lane = t & 63;
    int wv = __builtin_amdgcn_readfirstlane(t >> 6);
    int d = blockIdx.x * 4 + wv;
    if (d >= NN) return;
    const float* hr = h + (size_t)d * HID;
    float ea = b2[lane], eb = 0.f;
#pragma unroll 8
    for (int k = 0; k < HID; k += 2) {
        ea += hr[k] * w2t[k * 65 + lane];
        eb += hr[k + 1] * w2t[(k + 1) * 65 + lane];
    }
    float e = ea + eb;
    float m = e;
#pragma unroll
    for (int off = 32; off; off >>= 1) m = fmaxf(m, __shfl_xor(m, off));
    float ex = __expf(e - m);
    float s = ex;
#pragma unroll
    for (int off = 32; off; off >>= 1) s += __shfl_xor(s, off);
    float lsm = e - m - __logf(s);
    out[(size_t)d * ODIM + lane] = lsm;
    out[(size_t)NN * ODIM + (size_t)d * ODIM + lane] = e;
}

extern "C" void kernel_launch(void* const* d_in, const int* in_sizes, int n_in,
                              void* d_out, int out_size, void* d_ws, size_t ws_size,
                              hipStream_t stream) {
    const float* x    = (const float*)d_in[0];
    const int*   ei   = (const int*)d_in[1];
    const float* t1w  = (const float*)d_in[2];
    const float* t1b  = (const float*)d_in[3];
    const float* t2w  = (const float*)d_in[4];
    const float* t2b  = (const float*)d_in[5];
    const float* attl = (const float*)d_in[6];
    const float* attr = (const float*)d_in[7];
    float* out = (float*)d_out;

    const int* src = ei;
    const int* dst = ei + NE;

    char* ws = (char*)d_ws;
    size_t off = 0;
    auto alloc = [&](size_t bytes) { char* p = ws + off; off += (bytes + 255) & ~(size_t)255; return p; };
    float*  hA   = (float*)alloc((size_t)NN * HID * 4); // raw / h0
    float*  hB   = (float*)alloc((size_t)NN * HID * 4);
    float*  hC   = (float*)alloc((size_t)NN * HID * 4);
    ushort* wbf  = (ushort*)alloc((size_t)HID * IN_DIM * 2);
    int*    deg  = (int*)alloc((size_t)NN * 4);
    float*  dinv = (float*)alloc((size_t)NN * 4);
    int*    rowptr = (int*)alloc((size_t)(NN + 1) * 4);
    int*    cursor = (int*)alloc((size_t)NN * 4);
    int*    csr_src = (int*)alloc((size_t)NE * 4);
    int*    localScan = (int*)alloc((size_t)NN * 4);
    int*    blockSums = (int*)alloc((size_t)256 * 4);
    int*    blockOff  = (int*)alloc((size_t)256 * 4);
    float2* AD_A = (float2*)alloc((size_t)NN * 8);
    float*  AR_A = (float*)alloc((size_t)NN * 4);
    float2* AD_B = (float2*)alloc((size_t)NN * 8);
    float*  AR_B = (float*)alloc((size_t)NN * 4);
    (void)ws_size;

    hipMemsetAsync(deg, 0, (size_t)NN * 4, stream);

    dim3 blk(256);
    deg_kernel<<<(NE + 255) / 256, blk, 0, stream>>>(dst, deg);
    scanA_kernel<<<NBLK, blk, 0, stream>>>(deg, localScan, blockSums, dinv);
    scanB_kernel<<<1, blk, 0, stream>>>(blockSums, blockOff);
    scanC_kernel<<<NBLK, blk, 0, stream>>>(localScan, blockOff, rowptr, cursor);
    fill_kernel<<<(NE + 255) / 256, blk, 0, stream>>>(src, dst, cursor, csr_src);

    cvtw_kernel<<<(HID * IN_DIM + 255) / 256, blk, 0, stream>>>(t1w, wbf);
    // 64-row tiles: 782 blocks, one-shot 128KB staging, fused att0 epilogue
    gemm1_kernel<<<(NN + 63) / 64, blk, 0, stream>>>(x, wbf, t1b,
                                                     attl + 0 * HID, attr + 0 * HID,
                                                     dinv, hA, AD_A, AR_A);

    // L0: hA -> hB, epilogue computes layer-1 scalars into AD_B/AR_B
    agg_kernel<<<(NN + 3) / 4, blk, 0, stream>>>(hA, hA, hB, rowptr, csr_src, dinv,
                                                 AD_A, AR_A, attl + 1 * HID, attr + 1 * HID, AD_B, AR_B);
    // L1: hB -> hC, epilogue computes layer-2 scalars into AD_A/AR_A
    agg_kernel<<<(NN + 3) / 4, blk, 0, stream>>>(hB, hA, hC, rowptr, csr_src, dinv,
                                                 AD_B, AR_B, attl + 2 * HID, attr + 2 * HID, AD_A, AR_A);
    // L2: hC -> hB, no epilogue
    agg_kernel<<<(NN + 3) / 4, blk, 0, stream>>>(hC, hA, hB, rowptr, csr_src, dinv,
                                                 AD_A, AR_A, nullptr, nullptr, nullptr, nullptr);

    head_kernel<<<(NN + 3) / 4, blk, 0, stream>>>(hB, t2w, t2b, out);
}

// Round 5
// 457.901 us; speedup vs baseline: 1.1270x; 1.1270x over previous
//
#include <hip/hip_runtime.h>
#include <hip/hip_bf16.h>
#include <stdint.h>

#define NN 50000
#define NE 600000
#define IN_DIM 512
#define HID 128
#define ODIM 64
#define EPSV 0.1f
#define NBLK ((NN + 255) / 256)  // 196 scan blocks

typedef __attribute__((ext_vector_type(8))) short short8;
typedef __attribute__((ext_vector_type(4))) float f32x4;

__device__ __forceinline__ ushort f2bf(float f) {
    union { float f; uint32_t i; } v; v.f = f;
    uint32_t lsb = (v.i >> 16) & 1u;
    uint32_t r = v.i + 0x7fffu + lsb;
    return (ushort)(r >> 16);
}

__device__ __forceinline__ short8 pack8(float4 lo, float4 hi) {
    short8 r;
    r[0] = (short)f2bf(lo.x); r[1] = (short)f2bf(lo.y);
    r[2] = (short)f2bf(lo.z); r[3] = (short)f2bf(lo.w);
    r[4] = (short)f2bf(hi.x); r[5] = (short)f2bf(hi.y);
    r[6] = (short)f2bf(hi.z); r[7] = (short)f2bf(hi.w);
    return r;
}

// fast tanh: (e^2z - 1) / (e^2z + 1), clamped
__device__ __forceinline__ float fast_tanh(float z) {
    z = fminf(fmaxf(z, -15.f), 15.f);
    float t = __expf(2.f * z);
    return __fdividef(t - 1.f, t + 1.f);
}

// ---- degree count ----
__global__ __launch_bounds__(256) void deg_kernel(const int* __restrict__ dst, int* __restrict__ deg) {
    int e = blockIdx.x * 256 + threadIdx.x;
    if (e < NE) atomicAdd(&deg[dst[e]], 1);
}

// ---- scan phase A ----
__global__ __launch_bounds__(256) void scanA_kernel(const int* __restrict__ deg,
                                                    int* __restrict__ localScan,
                                                    int* __restrict__ blockSums,
                                                    float* __restrict__ dinv) {
    __shared__ int tmp[256];
    int t = threadIdx.x;
    int i = blockIdx.x * 256 + t;
    int v = (i < NN) ? deg[i] : 0;
    tmp[t] = v;
    __syncthreads();
    for (int off = 1; off < 256; off <<= 1) {
        int add = (t >= off) ? tmp[t - off] : 0;
        __syncthreads();
        tmp[t] += add;
        __syncthreads();
    }
    if (i < NN) {
        localScan[i] = tmp[t] - v;
        dinv[i] = (v > 0) ? (1.0f / sqrtf((float)v)) : 0.0f;
    }
    if (t == 255) blockSums[blockIdx.x] = tmp[255];
}

// ---- scan phase B ----
__global__ __launch_bounds__(256) void scanB_kernel(const int* __restrict__ blockSums,
                                                    int* __restrict__ blockOff) {
    __shared__ int tmp[256];
    int t = threadIdx.x;
    int v = (t < NBLK) ? blockSums[t] : 0;
    tmp[t] = v;
    __syncthreads();
    for (int off = 1; off < 256; off <<= 1) {
        int add = (t >= off) ? tmp[t - off] : 0;
        __syncthreads();
        tmp[t] += add;
        __syncthreads();
    }
    blockOff[t] = tmp[t] - v;
}

// ---- scan phase C ----
__global__ __launch_bounds__(256) void scanC_kernel(const int* __restrict__ localScan,
                                                    const int* __restrict__ blockOff,
                                                    int* __restrict__ rowptr,
                                                    int* __restrict__ cursor) {
    int i = blockIdx.x * 256 + threadIdx.x;
    if (i < NN) {
        int v = localScan[i] + blockOff[blockIdx.x];
        rowptr[i] = v;
        cursor[i] = v;
    }
    if (i == 0) rowptr[NN] = NE;
}

// ---- fill CSR ----
__global__ __launch_bounds__(256) void fill_kernel(const int* __restrict__ src, const int* __restrict__ dst,
                                                   int* __restrict__ cursor, int* __restrict__ csr_src) {
    int e = blockIdx.x * 256 + threadIdx.x;
    if (e < NE) {
        int d = dst[e];
        int slot = atomicAdd(&cursor[d], 1);
        csr_src[slot] = src[e];
    }
}

// ---- convert W1 fp32 -> bf16 ----
__global__ __launch_bounds__(256) void cvtw_kernel(const float* __restrict__ w, ushort* __restrict__ wbf) {
    int i = blockIdx.x * 256 + threadIdx.x;
    if (i < HID * IN_DIM) wbf[i] = f2bf(w[i]);
}

// ---- h0 = relu(x @ W1^T + b1), fused layer-0 attention scalars ----
// v5: B-in-LDS. Unified traffic model from rounds 0-4: total vector-memory
// bytes/CU are capped ~10 B/cyc (6.3 TB/s chip) regardless of cache level.
// All prior variants moved ~528 MB through L1 (102 x + 400 B-rereads + 26
// writes) -> 84 us floor. Fix: stage B (bf16 W1, 128 KB) ONCE per block in
// LDS; 1024-thread blocks (16 waves x 16 rows = 256 rows) amortize staging
// (B traffic 400 -> 25 MB; total ~153 MB -> ~31 us). A keeps the v2
// register-stream (depth-2 prefetch); its vmcnt chain no longer entangles
// with B (now lgkmcnt). B LDS is 16B-granule XOR-swizzled (g ^= row&7) so
// fragment ds_read_b128 is conflict-free; staging writes are full permuted
// rows (also conflict-free). Math path identical -> same absmax.
__global__ __launch_bounds__(1024, 4) void gemm1_kernel(const float* __restrict__ x,
                                                        const ushort* __restrict__ wbf,
                                                        const float* __restrict__ b,
                                                        const float* __restrict__ attl,
                                                        const float* __restrict__ attr,
                                                        const float* __restrict__ dinv,
                                                        float* __restrict__ h,
                                                        float2* __restrict__ AD,
                                                        float* __restrict__ AR) {
    __shared__ __attribute__((aligned(16))) ushort b_sm[HID * IN_DIM]; // 128 KB
    int t = threadIdx.x;
    int wv = __builtin_amdgcn_readfirstlane(t >> 6);   // 0..15
    int lane = t & 63;
    int m0 = blockIdx.x * 256;

    // ---- stage B: 8 rounds x 1024 threads x 16B granule, row-XOR swizzle ----
    {
        uint4 bg[8];
#pragma unroll
        for (int rnd = 0; rnd < 8; ++rnd)
            bg[rnd] = *(const uint4*)(wbf + (size_t)(rnd * 1024 + t) * 8);
#pragma unroll
        for (int rnd = 0; rnd < 8; ++rnd) {
            int G = rnd * 1024 + t;            // global granule 0..8191
            int row = G >> 6;                  // B row 0..127
            int g = G & 63;                    // granule within row
            *(uint4*)&b_sm[(size_t)((row << 6) | (g ^ (row & 7))) * 8] = bg[rnd];
        }
    }
    __syncthreads();

    // fragment map
    int rsel = lane & 15;          // A row within stripe / B row select
    int koff = (lane >> 4) * 8;    // K sub-offset (floats / ushorts)
    int sw = rsel & 7;             // B row swizzle key
    int qg = koff >> 3;            // quarter-granule index 0..3
    int row = m0 + wv * 16 + rsel; if (row >= NN) row = NN - 1;
    const float* xr = x + (size_t)row * IN_DIM + koff;

    f32x4 acc[8];
#pragma unroll
    for (int tt = 0; tt < 8; ++tt) acc[tt] = (f32x4){0.f, 0.f, 0.f, 0.f};

    // depth-2 prefetch: two K-steps (2 x 8 floats/lane) in flight
    float4 c0lo = *(const float4*)(xr);
    float4 c0hi = *(const float4*)(xr + 4);
    float4 c1lo = *(const float4*)(xr + 32);
    float4 c1hi = *(const float4*)(xr + 36);

#pragma unroll
    for (int ks = 0; ks < 16; ks += 2) {
        float4 n0lo, n0hi, n1lo, n1hi;
        bool more = (ks + 2 < 16);
        if (more) {
            n0lo = *(const float4*)(xr + (ks + 2) * 32);
            n0hi = *(const float4*)(xr + (ks + 2) * 32 + 4);
            n1lo = *(const float4*)(xr + (ks + 3) * 32);
            n1hi = *(const float4*)(xr + (ks + 3) * 32 + 4);
        }
        short8 a0 = pack8(c0lo, c0hi);
#pragma unroll
        for (int tt = 0; tt < 8; ++tt) {
            int rb = tt * 16 + rsel;
            short8 bf = *(const short8*)&b_sm[(size_t)(rb << 9) + (size_t)(((ks * 4 + qg) ^ sw) << 3)];
            acc[tt] = __builtin_amdgcn_mfma_f32_16x16x32_bf16(a0, bf, acc[tt], 0, 0, 0);
        }
        short8 a1 = pack8(c1lo, c1hi);
#pragma unroll
        for (int tt = 0; tt < 8; ++tt) {
            int rb = tt * 16 + rsel;
            short8 bf = *(const short8*)&b_sm[(size_t)(rb << 9) + (size_t)((((ks + 1) * 4 + qg) ^ sw) << 3)];
            acc[tt] = __builtin_amdgcn_mfma_f32_16x16x32_bf16(a1, bf, acc[tt], 0, 0, 0);
        }
        if (more) { c0lo = n0lo; c0hi = n0hi; c1lo = n1lo; c1hi = n1hi; }
    }

    // epilogue: bias + relu + store + fused layer-0 attention scalars
    int rbase = (lane >> 4) * 4;
    int col0 = lane & 15;
    float alv[8], arv[8], bias[8];
#pragma unroll
    for (int tt = 0; tt < 8; ++tt) {
        alv[tt]  = attl[tt * 16 + col0];
        arv[tt]  = attr[tt * 16 + col0];
        bias[tt] = b[tt * 16 + col0];
    }
#pragma unroll
    for (int r = 0; r < 4; ++r) {
        int rrow = m0 + wv * 16 + rbase + r;
        float p = 0.f, q = 0.f;
#pragma unroll
        for (int tt = 0; tt < 8; ++tt) {
            float v = acc[tt][r] + bias[tt];
            v = v > 0.f ? v : 0.f;
            if (rrow < NN) h[(size_t)rrow * HID + tt * 16 + col0] = v;
            p += v * alv[tt];
            q += v * arv[tt];
        }
#pragma unroll
        for (int off = 8; off; off >>= 1) { p += __shfl_xor(p, off); q += __shfl_xor(q, off); }
        if (col0 == 0 && rrow < NN) {
            float2 vv; vv.x = p; vv.y = dinv[rrow];
            AD[rrow] = vv;
            AR[rrow] = q;
        }
    }
}

// ---- FAConv aggregation: wave per dst node, 8-deep edge unroll for MLP ----
__global__ __launch_bounds__(256) void agg_kernel(const float* __restrict__ h,
                                                  const float* __restrict__ raw,
                                                  float* __restrict__ hn,
                                                  const int* __restrict__ rowptr,
                                                  const int* __restrict__ csr_src,
                                                  const float* __restrict__ dinv,
                                                  const float2* __restrict__ AD,
                                                  const float* __restrict__ AR,
                                                  const float* __restrict__ attl_next,
                                                  const float* __restrict__ attr_next,
                                                  float2* __restrict__ ADout,
                                                  float* __restrict__ ARout) {
    int wv = __builtin_amdgcn_readfirstlane(threadIdx.x >> 6);
    int lane = threadIdx.x & 63;
    int d = blockIdx.x * 4 + wv;
    if (d >= NN) return;
    const float2* h2 = (const float2*)h;
    float ar_d = AR[d];
    float dinv_d = dinv[d];
    float2 rawd = ((const float2*)raw)[(size_t)d * 64 + lane];
    float accx = EPSV * rawd.x, accy = EPSV * rawd.y;
    int e = rowptr[d], e1 = rowptr[d + 1];
    // ---- 8-deep: 1 broadcast index load + 8 concurrent 512B row loads ----
    for (; e + 8 <= e1; e += 8) {
        int sv = csr_src[e + (lane & 7)];
        int s0 = __builtin_amdgcn_readfirstlane(__shfl(sv, 0));
        int s1 = __builtin_amdgcn_readfirstlane(__shfl(sv, 1));
        int s2 = __builtin_amdgcn_readfirstlane(__shfl(sv, 2));
        int s3 = __builtin_amdgcn_readfirstlane(__shfl(sv, 3));
        int s4 = __builtin_amdgcn_readfirstlane(__shfl(sv, 4));
        int s5 = __builtin_amdgcn_readfirstlane(__shfl(sv, 5));
        int s6 = __builtin_amdgcn_readfirstlane(__shfl(sv, 6));
        int s7 = __builtin_amdgcn_readfirstlane(__shfl(sv, 7));
        float2 ad0 = AD[s0], ad1 = AD[s1], ad2 = AD[s2], ad3 = AD[s3];
        float2 ad4 = AD[s4], ad5 = AD[s5], ad6 = AD[s6], ad7 = AD[s7];
        float2 v0 = h2[(size_t)s0 * 64 + lane];
        float2 v1 = h2[(size_t)s1 * 64 + lane];
        float2 v2 = h2[(size_t)s2 * 64 + lane];
        float2 v3 = h2[(size_t)s3 * 64 + lane];
        float2 v4 = h2[(size_t)s4 * 64 + lane];
        float2 v5 = h2[(size_t)s5 * 64 + lane];
        float2 v6 = h2[(size_t)s6 * 64 + lane];
        float2 v7 = h2[(size_t)s7 * 64 + lane];
        float w0 = fast_tanh(ad0.x + ar_d) * ad0.y * dinv_d;
        float w1 = fast_tanh(ad1.x + ar_d) * ad1.y * dinv_d;
        float w2 = fast_tanh(ad2.x + ar_d) * ad2.y * dinv_d;
        float w3 = fast_tanh(ad3.x + ar_d) * ad3.y * dinv_d;
        float w4 = fast_tanh(ad4.x + ar_d) * ad4.y * dinv_d;
        float w5 = fast_tanh(ad5.x + ar_d) * ad5.y * dinv_d;
        float w6 = fast_tanh(ad6.x + ar_d) * ad6.y * dinv_d;
        float w7 = fast_tanh(ad7.x + ar_d) * ad7.y * dinv_d;
        accx += w0 * v0.x + w1 * v1.x + w2 * v2.x + w3 * v3.x;
        accy += w0 * v0.y + w1 * v1.y + w2 * v2.y + w3 * v3.y;
        accx += w4 * v4.x + w5 * v5.x + w6 * v6.x + w7 * v7.x;
        accy += w4 * v4.y + w5 * v5.y + w6 * v6.y + w7 * v7.y;
    }
    for (; e + 4 <= e1; e += 4) {
        int sv = csr_src[e + (lane & 3)];
        int s0 = __builtin_amdgcn_readfirstlane(__shfl(sv, 0));
        int s1 = __builtin_amdgcn_readfirstlane(__shfl(sv, 1));
        int s2 = __builtin_amdgcn_readfirstlane(__shfl(sv, 2));
        int s3 = __builtin_amdgcn_readfirstlane(__shfl(sv, 3));
        float2 ad0 = AD[s0], ad1 = AD[s1], ad2 = AD[s2], ad3 = AD[s3];
        float2 v0 = h2[(size_t)s0 * 64 + lane];
        float2 v1 = h2[(size_t)s1 * 64 + lane];
        float2 v2 = h2[(size_t)s2 * 64 + lane];
        float2 v3 = h2[(size_t)s3 * 64 + lane];
        float w0 = fast_tanh(ad0.x + ar_d) * ad0.y * dinv_d;
        float w1 = fast_tanh(ad1.x + ar_d) * ad1.y * dinv_d;
        float w2 = fast_tanh(ad2.x + ar_d) * ad2.y * dinv_d;
        float w3 = fast_tanh(ad3.x + ar_d) * ad3.y * dinv_d;
        accx += w0 * v0.x + w1 * v1.x + w2 * v2.x + w3 * v3.x;
        accy += w0 * v0.y + w1 * v1.y + w2 * v2.y + w3 * v3.y;
    }
    for (; e < e1; ++e) {
        int s = __builtin_amdgcn_readfirstlane(csr_src[e]);
        float2 ad = AD[s];
        float2 v = h2[(size_t)s * 64 + lane];
        float w = fast_tanh(ad.x + ar_d) * ad.y * dinv_d;
        accx += w * v.x;
        accy += w * v.y;
    }
    float2 o; o.x = accx; o.y = accy;
    ((float2*)hn)[(size_t)d * 64 + lane] = o;
    if (attl_next) {
        float al0 = attl_next[2 * lane], al1 = attl_next[2 * lane + 1];
        float ar0 = attr_next[2 * lane], ar1 = attr_next[2 * lane + 1];
        float p = accx * al0 + accy * al1;
        float q = accx * ar0 + accy * ar1;
#pragma unroll
        for (int off = 32; off; off >>= 1) { p += __shfl_xor(p, off); q += __shfl_xor(q, off); }
        if (lane == 0) {
            float2 v; v.x = p; v.y = dinv_d;
            ADout[d] = v;
            ARout[d] = q;
        }
    }
}

// ---- head: emb = h @ W2^T + b2; out0 = log_softmax(emb); out1 = emb ----
__global__ __launch_bounds__(256) void head_kernel(const float* __restrict__ h,
                                                   const float* __restrict__ w2,
                                                   const float* __restrict__ b2,
                                                   float* __restrict__ out) {
    __shared__ float w2t[HID * 65];
    int t = threadIdx.x;
    for (int i = t; i < HID * ODIM; i += 256) {
        int j = i >> 7, k = i & 127;
        w2t[k * 65 + j] = w2[i];
    }
    __syncthreads();
    int lane = t & 63;
    int wv = __builtin_amdgcn_readfirstlane(t >> 6);
    int d = blockIdx.x * 4 + wv;
    if (d >= NN) return;
    const float* hr = h + (size_t)d * HID;
    float ea = b2[lane], eb = 0.f;
#pragma unroll 8
    for (int k = 0; k < HID; k += 2) {
        ea += hr[k] * w2t[k * 65 + lane];
        eb += hr[k + 1] * w2t[(k + 1) * 65 + lane];
    }
    float e = ea + eb;
    float m = e;
#pragma unroll
    for (int off = 32; off; off >>= 1) m = fmaxf(m, __shfl_xor(m, off));
    float ex = __expf(e - m);
    float s = ex;
#pragma unroll
    for (int off = 32; off; off >>= 1) s += __shfl_xor(s, off);
    float lsm = e - m - __logf(s);
    out[(size_t)d * ODIM + lane] = lsm;
    out[(size_t)NN * ODIM + (size_t)d * ODIM + lane] = e;
}

extern "C" void kernel_launch(void* const* d_in, const int* in_sizes, int n_in,
                              void* d_out, int out_size, void* d_ws, size_t ws_size,
                              hipStream_t stream) {
    const float* x    = (const float*)d_in[0];
    const int*   ei   = (const int*)d_in[1];
    const float* t1w  = (const float*)d_in[2];
    const float* t1b  = (const float*)d_in[3];
    const float* t2w  = (const float*)d_in[4];
    const float* t2b  = (const float*)d_in[5];
    const float* attl = (const float*)d_in[6];
    const float* attr = (const float*)d_in[7];
    float* out = (float*)d_out;

    const int* src = ei;
    const int* dst = ei + NE;

    char* ws = (char*)d_ws;
    size_t off = 0;
    auto alloc = [&](size_t bytes) { char* p = ws + off; off += (bytes + 255) & ~(size_t)255; return p; };
    float*  hA   = (float*)alloc((size_t)NN * HID * 4); // raw / h0
    float*  hB   = (float*)alloc((size_t)NN * HID * 4);
    float*  hC   = (float*)alloc((size_t)NN * HID * 4);
    ushort* wbf  = (ushort*)alloc((size_t)HID * IN_DIM * 2);
    int*    deg  = (int*)alloc((size_t)NN * 4);
    float*  dinv = (float*)alloc((size_t)NN * 4);
    int*    rowptr = (int*)alloc((size_t)(NN + 1) * 4);
    int*    cursor = (int*)alloc((size_t)NN * 4);
    int*    csr_src = (int*)alloc((size_t)NE * 4);
    int*    localScan = (int*)alloc((size_t)NN * 4);
    int*    blockSums = (int*)alloc((size_t)256 * 4);
    int*    blockOff  = (int*)alloc((size_t)256 * 4);
    float2* AD_A = (float2*)alloc((size_t)NN * 8);
    float*  AR_A = (float*)alloc((size_t)NN * 4);
    float2* AD_B = (float2*)alloc((size_t)NN * 8);
    float*  AR_B = (float*)alloc((size_t)NN * 4);
    (void)ws_size;

    hipMemsetAsync(deg, 0, (size_t)NN * 4, stream);

    dim3 blk(256);
    deg_kernel<<<(NE + 255) / 256, blk, 0, stream>>>(dst, deg);
    scanA_kernel<<<NBLK, blk, 0, stream>>>(deg, localScan, blockSums, dinv);
    scanB_kernel<<<1, blk, 0, stream>>>(blockSums, blockOff);
    scanC_kernel<<<NBLK, blk, 0, stream>>>(localScan, blockOff, rowptr, cursor);
    fill_kernel<<<(NE + 255) / 256, blk, 0, stream>>>(src, dst, cursor, csr_src);

    cvtw_kernel<<<(HID * IN_DIM + 255) / 256, blk, 0, stream>>>(t1w, wbf);
    // 196 blocks x 1024 threads, 256 rows each, B staged once per block
    gemm1_kernel<<<(NN + 255) / 256, dim3(1024), 0, stream>>>(x, wbf, t1b,
                                                              attl + 0 * HID, attr + 0 * HID,
                                                              dinv, hA, AD_A, AR_A);

    // L0: hA -> hB, epilogue computes layer-1 scalars into AD_B/AR_B
    agg_kernel<<<(NN + 3) / 4, blk, 0, stream>>>(hA, hA, hB, rowptr, csr_src, dinv,
                                                 AD_A, AR_A, attl + 1 * HID, attr + 1 * HID, AD_B, AR_B);
    // L1: hB -> hC, epilogue computes layer-2 scalars into AD_A/AR_A
    agg_kernel<<<(NN + 3) / 4, blk, 0, stream>>>(hB, hA, hC, rowptr, csr_src, dinv,
                                                 AD_B, AR_B, attl + 2 * HID, attr + 2 * HID, AD_A, AR_A);
    // L2: hC -> hB, no epilogue
    agg_kernel<<<(NN + 3) / 4, blk, 0, stream>>>(hC, hA, hB, rowptr, csr_src, dinv,
                                                 AD_A, AR_A, nullptr, nullptr, nullptr, nullptr);

    head_kernel<<<(NN + 3) / 4, blk, 0, stream>>>(hB, t2w, t2b, out);
}

// Round 6
// 413.931 us; speedup vs baseline: 1.2467x; 1.1062x over previous
//
#include <hip/hip_runtime.h>
#include <hip/hip_bf16.h>
#include <stdint.h>

#define NN 50000
#define NE 600000
#define IN_DIM 512
#define HID 128
#define ODIM 64
#define EPSV 0.1f
#define NBLK ((NN + 255) / 256)  // 196 scan blocks

typedef __attribute__((ext_vector_type(8))) short short8;
typedef __attribute__((ext_vector_type(4))) float f32x4;

__device__ __forceinline__ ushort f2bf(float f) {
    union { float f; uint32_t i; } v; v.f = f;
    uint32_t lsb = (v.i >> 16) & 1u;
    uint32_t r = v.i + 0x7fffu + lsb;
    return (ushort)(r >> 16);
}

__device__ __forceinline__ float bf2f(ushort u) {
    union { uint32_t i; float f; } v; v.i = ((uint32_t)u) << 16;
    return v.f;
}

__device__ __forceinline__ short8 pack8(float4 lo, float4 hi) {
    short8 r;
    r[0] = (short)f2bf(lo.x); r[1] = (short)f2bf(lo.y);
    r[2] = (short)f2bf(lo.z); r[3] = (short)f2bf(lo.w);
    r[4] = (short)f2bf(hi.x); r[5] = (short)f2bf(hi.y);
    r[6] = (short)f2bf(hi.z); r[7] = (short)f2bf(hi.w);
    return r;
}

// fast tanh: (e^2z - 1) / (e^2z + 1), clamped
__device__ __forceinline__ float fast_tanh(float z) {
    z = fminf(fmaxf(z, -15.f), 15.f);
    float t = __expf(2.f * z);
    return __fdividef(t - 1.f, t + 1.f);
}

// ---- degree count ----
__global__ __launch_bounds__(256) void deg_kernel(const int* __restrict__ dst, int* __restrict__ deg) {
    int e = blockIdx.x * 256 + threadIdx.x;
    if (e < NE) atomicAdd(&deg[dst[e]], 1);
}

// ---- scan phase A ----
__global__ __launch_bounds__(256) void scanA_kernel(const int* __restrict__ deg,
                                                    int* __restrict__ localScan,
                                                    int* __restrict__ blockSums,
                                                    float* __restrict__ dinv) {
    __shared__ int tmp[256];
    int t = threadIdx.x;
    int i = blockIdx.x * 256 + t;
    int v = (i < NN) ? deg[i] : 0;
    tmp[t] = v;
    __syncthreads();
    for (int off = 1; off < 256; off <<= 1) {
        int add = (t >= off) ? tmp[t - off] : 0;
        __syncthreads();
        tmp[t] += add;
        __syncthreads();
    }
    if (i < NN) {
        localScan[i] = tmp[t] - v;
        dinv[i] = (v > 0) ? (1.0f / sqrtf((float)v)) : 0.0f;
    }
    if (t == 255) blockSums[blockIdx.x] = tmp[255];
}

// ---- scan phase B ----
__global__ __launch_bounds__(256) void scanB_kernel(const int* __restrict__ blockSums,
                                                    int* __restrict__ blockOff) {
    __shared__ int tmp[256];
    int t = threadIdx.x;
    int v = (t < NBLK) ? blockSums[t] : 0;
    tmp[t] = v;
    __syncthreads();
    for (int off = 1; off < 256; off <<= 1) {
        int add = (t >= off) ? tmp[t - off] : 0;
        __syncthreads();
        tmp[t] += add;
        __syncthreads();
    }
    blockOff[t] = tmp[t] - v;
}

// ---- scan phase C ----
__global__ __launch_bounds__(256) void scanC_kernel(const int* __restrict__ localScan,
                                                    const int* __restrict__ blockOff,
                                                    int* __restrict__ rowptr,
                                                    int* __restrict__ cursor) {
    int i = blockIdx.x * 256 + threadIdx.x;
    if (i < NN) {
        int v = localScan[i] + blockOff[blockIdx.x];
        rowptr[i] = v;
        cursor[i] = v;
    }
    if (i == 0) rowptr[NN] = NE;
}

// ---- fill CSR ----
__global__ __launch_bounds__(256) void fill_kernel(const int* __restrict__ src, const int* __restrict__ dst,
                                                   int* __restrict__ cursor, int* __restrict__ csr_src) {
    int e = blockIdx.x * 256 + threadIdx.x;
    if (e < NE) {
        int d = dst[e];
        int slot = atomicAdd(&cursor[d], 1);
        csr_src[slot] = src[e];
    }
}

// ---- convert W1 fp32 -> bf16 ----
__global__ __launch_bounds__(256) void cvtw_kernel(const float* __restrict__ w, ushort* __restrict__ wbf) {
    int i = blockIdx.x * 256 + threadIdx.x;
    if (i < HID * IN_DIM) wbf[i] = f2bf(w[i]);
}

// ---- h0 = relu(x @ W1^T + b1), fused layer-0 attention scalars ----
// v5 (kept): B staged once per 1024-thread block -> B traffic 400 -> 25 MB.
__global__ __launch_bounds__(1024, 4) void gemm1_kernel(const float* __restrict__ x,
                                                        const ushort* __restrict__ wbf,
                                                        const float* __restrict__ b,
                                                        const float* __restrict__ attl,
                                                        const float* __restrict__ attr,
                                                        const float* __restrict__ dinv,
                                                        float* __restrict__ h,
                                                        float2* __restrict__ AD,
                                                        float* __restrict__ AR) {
    __shared__ __attribute__((aligned(16))) ushort b_sm[HID * IN_DIM]; // 128 KB
    int t = threadIdx.x;
    int wv = __builtin_amdgcn_readfirstlane(t >> 6);   // 0..15
    int lane = t & 63;
    int m0 = blockIdx.x * 256;

    // ---- stage B: 8 rounds x 1024 threads x 16B granule, row-XOR swizzle ----
    {
        uint4 bg[8];
#pragma unroll
        for (int rnd = 0; rnd < 8; ++rnd)
            bg[rnd] = *(const uint4*)(wbf + (size_t)(rnd * 1024 + t) * 8);
#pragma unroll
        for (int rnd = 0; rnd < 8; ++rnd) {
            int G = rnd * 1024 + t;            // global granule 0..8191
            int row = G >> 6;                  // B row 0..127
            int g = G & 63;                    // granule within row
            *(uint4*)&b_sm[(size_t)((row << 6) | (g ^ (row & 7))) * 8] = bg[rnd];
        }
    }
    __syncthreads();

    // fragment map
    int rsel = lane & 15;          // A row within stripe / B row select
    int koff = (lane >> 4) * 8;    // K sub-offset (floats / ushorts)
    int sw = rsel & 7;             // B row swizzle key
    int qg = koff >> 3;            // quarter-granule index 0..3
    int row = m0 + wv * 16 + rsel; if (row >= NN) row = NN - 1;
    const float* xr = x + (size_t)row * IN_DIM + koff;

    f32x4 acc[8];
#pragma unroll
    for (int tt = 0; tt < 8; ++tt) acc[tt] = (f32x4){0.f, 0.f, 0.f, 0.f};

    // depth-2 prefetch: two K-steps (2 x 8 floats/lane) in flight
    float4 c0lo = *(const float4*)(xr);
    float4 c0hi = *(const float4*)(xr + 4);
    float4 c1lo = *(const float4*)(xr + 32);
    float4 c1hi = *(const float4*)(xr + 36);

#pragma unroll
    for (int ks = 0; ks < 16; ks += 2) {
        float4 n0lo, n0hi, n1lo, n1hi;
        bool more = (ks + 2 < 16);
        if (more) {
            n0lo = *(const float4*)(xr + (ks + 2) * 32);
            n0hi = *(const float4*)(xr + (ks + 2) * 32 + 4);
            n1lo = *(const float4*)(xr + (ks + 3) * 32);
            n1hi = *(const float4*)(xr + (ks + 3) * 32 + 4);
        }
        short8 a0 = pack8(c0lo, c0hi);
#pragma unroll
        for (int tt = 0; tt < 8; ++tt) {
            int rb = tt * 16 + rsel;
            short8 bf = *(const short8*)&b_sm[(size_t)(rb << 9) + (size_t)(((ks * 4 + qg) ^ sw) << 3)];
            acc[tt] = __builtin_amdgcn_mfma_f32_16x16x32_bf16(a0, bf, acc[tt], 0, 0, 0);
        }
        short8 a1 = pack8(c1lo, c1hi);
#pragma unroll
        for (int tt = 0; tt < 8; ++tt) {
            int rb = tt * 16 + rsel;
            short8 bf = *(const short8*)&b_sm[(size_t)(rb << 9) + (size_t)((((ks + 1) * 4 + qg) ^ sw) << 3)];
            acc[tt] = __builtin_amdgcn_mfma_f32_16x16x32_bf16(a1, bf, acc[tt], 0, 0, 0);
        }
        if (more) { c0lo = n0lo; c0hi = n0hi; c1lo = n1lo; c1hi = n1hi; }
    }

    // epilogue: bias + relu + store + fused layer-0 attention scalars
    int rbase = (lane >> 4) * 4;
    int col0 = lane & 15;
    float alv[8], arv[8], bias[8];
#pragma unroll
    for (int tt = 0; tt < 8; ++tt) {
        alv[tt]  = attl[tt * 16 + col0];
        arv[tt]  = attr[tt * 16 + col0];
        bias[tt] = b[tt * 16 + col0];
    }
#pragma unroll
    for (int r = 0; r < 4; ++r) {
        int rrow = m0 + wv * 16 + rbase + r;
        float p = 0.f, q = 0.f;
#pragma unroll
        for (int tt = 0; tt < 8; ++tt) {
            float v = acc[tt][r] + bias[tt];
            v = v > 0.f ? v : 0.f;
            if (rrow < NN) h[(size_t)rrow * HID + tt * 16 + col0] = v;
            p += v * alv[tt];
            q += v * arv[tt];
        }
#pragma unroll
        for (int off = 8; off; off >>= 1) { p += __shfl_xor(p, off); q += __shfl_xor(q, off); }
        if (col0 == 0 && rrow < NN) {
            float2 vv; vv.x = p; vv.y = dinv[rrow];
            AD[rrow] = vv;
            AR[rrow] = q;
        }
    }
}

// ---- FAConv aggregation: wave per dst node, 8-deep edge unroll for MLP ----
__global__ __launch_bounds__(256) void agg_kernel(const float* __restrict__ h,
                                                  const float* __restrict__ raw,
                                                  float* __restrict__ hn,
                                                  const int* __restrict__ rowptr,
                                                  const int* __restrict__ csr_src,
                                                  const float* __restrict__ dinv,
                                                  const float2* __restrict__ AD,
                                                  const float* __restrict__ AR,
                                                  const float* __restrict__ attl_next,
                                                  const float* __restrict__ attr_next,
                                                  float2* __restrict__ ADout,
                                                  float* __restrict__ ARout) {
    int wv = __builtin_amdgcn_readfirstlane(threadIdx.x >> 6);
    int lane = threadIdx.x & 63;
    int d = blockIdx.x * 4 + wv;
    if (d >= NN) return;
    const float2* h2 = (const float2*)h;
    float ar_d = AR[d];
    float dinv_d = dinv[d];
    float2 rawd = ((const float2*)raw)[(size_t)d * 64 + lane];
    float accx = EPSV * rawd.x, accy = EPSV * rawd.y;
    int e = rowptr[d], e1 = rowptr[d + 1];
    // ---- 8-deep: 1 broadcast index load + 8 concurrent 512B row loads ----
    for (; e + 8 <= e1; e += 8) {
        int sv = csr_src[e + (lane & 7)];
        int s0 = __builtin_amdgcn_readfirstlane(__shfl(sv, 0));
        int s1 = __builtin_amdgcn_readfirstlane(__shfl(sv, 1));
        int s2 = __builtin_amdgcn_readfirstlane(__shfl(sv, 2));
        int s3 = __builtin_amdgcn_readfirstlane(__shfl(sv, 3));
        int s4 = __builtin_amdgcn_readfirstlane(__shfl(sv, 4));
        int s5 = __builtin_amdgcn_readfirstlane(__shfl(sv, 5));
        int s6 = __builtin_amdgcn_readfirstlane(__shfl(sv, 6));
        int s7 = __builtin_amdgcn_readfirstlane(__shfl(sv, 7));
        float2 ad0 = AD[s0], ad1 = AD[s1], ad2 = AD[s2], ad3 = AD[s3];
        float2 ad4 = AD[s4], ad5 = AD[s5], ad6 = AD[s6], ad7 = AD[s7];
        float2 v0 = h2[(size_t)s0 * 64 + lane];
        float2 v1 = h2[(size_t)s1 * 64 + lane];
        float2 v2 = h2[(size_t)s2 * 64 + lane];
        float2 v3 = h2[(size_t)s3 * 64 + lane];
        float2 v4 = h2[(size_t)s4 * 64 + lane];
        float2 v5 = h2[(size_t)s5 * 64 + lane];
        float2 v6 = h2[(size_t)s6 * 64 + lane];
        float2 v7 = h2[(size_t)s7 * 64 + lane];
        float w0 = fast_tanh(ad0.x + ar_d) * ad0.y * dinv_d;
        float w1 = fast_tanh(ad1.x + ar_d) * ad1.y * dinv_d;
        float w2 = fast_tanh(ad2.x + ar_d) * ad2.y * dinv_d;
        float w3 = fast_tanh(ad3.x + ar_d) * ad3.y * dinv_d;
        float w4 = fast_tanh(ad4.x + ar_d) * ad4.y * dinv_d;
        float w5 = fast_tanh(ad5.x + ar_d) * ad5.y * dinv_d;
        float w6 = fast_tanh(ad6.x + ar_d) * ad6.y * dinv_d;
        float w7 = fast_tanh(ad7.x + ar_d) * ad7.y * dinv_d;
        accx += w0 * v0.x + w1 * v1.x + w2 * v2.x + w3 * v3.x;
        accy += w0 * v0.y + w1 * v1.y + w2 * v2.y + w3 * v3.y;
        accx += w4 * v4.x + w5 * v5.x + w6 * v6.x + w7 * v7.x;
        accy += w4 * v4.y + w5 * v5.y + w6 * v6.y + w7 * v7.y;
    }
    for (; e + 4 <= e1; e += 4) {
        int sv = csr_src[e + (lane & 3)];
        int s0 = __builtin_amdgcn_readfirstlane(__shfl(sv, 0));
        int s1 = __builtin_amdgcn_readfirstlane(__shfl(sv, 1));
        int s2 = __builtin_amdgcn_readfirstlane(__shfl(sv, 2));
        int s3 = __builtin_amdgcn_readfirstlane(__shfl(sv, 3));
        float2 ad0 = AD[s0], ad1 = AD[s1], ad2 = AD[s2], ad3 = AD[s3];
        float2 v0 = h2[(size_t)s0 * 64 + lane];
        float2 v1 = h2[(size_t)s1 * 64 + lane];
        float2 v2 = h2[(size_t)s2 * 64 + lane];
        float2 v3 = h2[(size_t)s3 * 64 + lane];
        float w0 = fast_tanh(ad0.x + ar_d) * ad0.y * dinv_d;
        float w1 = fast_tanh(ad1.x + ar_d) * ad1.y * dinv_d;
        float w2 = fast_tanh(ad2.x + ar_d) * ad2.y * dinv_d;
        float w3 = fast_tanh(ad3.x + ar_d) * ad3.y * dinv_d;
        accx += w0 * v0.x + w1 * v1.x + w2 * v2.x + w3 * v3.x;
        accy += w0 * v0.y + w1 * v1.y + w2 * v2.y + w3 * v3.y;
    }
    for (; e < e1; ++e) {
        int s = __builtin_amdgcn_readfirstlane(csr_src[e]);
        float2 ad = AD[s];
        float2 v = h2[(size_t)s * 64 + lane];
        float w = fast_tanh(ad.x + ar_d) * ad.y * dinv_d;
        accx += w * v.x;
        accy += w * v.y;
    }
    float2 o; o.x = accx; o.y = accy;
    ((float2*)hn)[(size_t)d * 64 + lane] = o;
    if (attl_next) {
        float al0 = attl_next[2 * lane], al1 = attl_next[2 * lane + 1];
        float ar0 = attr_next[2 * lane], ar1 = attr_next[2 * lane + 1];
        float p = accx * al0 + accy * al1;
        float q = accx * ar0 + accy * ar1;
#pragma unroll
        for (int off = 32; off; off >>= 1) { p += __shfl_xor(p, off); q += __shfl_xor(q, off); }
        if (lane == 0) {
            float2 v; v.x = p; v.y = dinv_d;
            ADout[d] = v;
            ARout[d] = q;
        }
    }
}

// ---- head: emb = h @ W2^T + b2; out0 = log_softmax(emb); out1 = emb ----
// v6: split-bf16 MFMA GEMM. Old head staged w2 per 4-node block (400 MB
// redundant traffic) and re-read 32 KB of w2t from LDS per node (~21 us
// LDS floor). New: 391 blocks x 256 threads, wave = 32 nodes; w2 staged
// once per block as hi/lo bf16 (granule-swizzled, 32 KB); B-frags amortize
// over the M-tile; h read as float4. 3-term split product keeps ~16 mantissa
// bits -> error ~2^-16 relative, absmax unchanged.
__global__ __launch_bounds__(256) void head_kernel(const float* __restrict__ h,
                                                   const float* __restrict__ w2,
                                                   const float* __restrict__ b2,
                                                   float* __restrict__ out) {
    __shared__ __attribute__((aligned(16))) ushort bhi_sm[ODIM * HID]; // 16 KB
    __shared__ __attribute__((aligned(16))) ushort blo_sm[ODIM * HID]; // 16 KB
    int t = threadIdx.x;
    int wv = __builtin_amdgcn_readfirstlane(t >> 6);
    int lane = t & 63;

    // ---- stage w2 -> hi/lo bf16, 16B-granule XOR swizzle (key = row&7) ----
    {
        int j = t >> 2;                 // output col 0..63
        int k0 = (t & 3) * 32;          // k chunk
        const float* wr = w2 + (size_t)j * HID + k0;
#pragma unroll
        for (int gg = 0; gg < 4; ++gg) {
            float4 a4 = *(const float4*)(wr + gg * 8);
            float4 b4 = *(const float4*)(wr + gg * 8 + 4);
            float vals[8] = {a4.x, a4.y, a4.z, a4.w, b4.x, b4.y, b4.z, b4.w};
            short8 vhi, vlo;
#pragma unroll
            for (int e = 0; e < 8; ++e) {
                ushort hu = f2bf(vals[e]);
                ushort lu = f2bf(vals[e] - bf2f(hu));
                vhi[e] = (short)hu; vlo[e] = (short)lu;
            }
            int g = (t & 3) * 4 + gg;          // granule 0..15
            int p = g ^ (j & 7);
            *(short8*)&bhi_sm[(size_t)j * HID + p * 8] = vhi;
            *(short8*)&blo_sm[(size_t)j * HID + p * 8] = vlo;
        }
    }
    __syncthreads();

    int rsel = lane & 15;
    int q16 = lane >> 4;            // 0..3
    int koff = q16 * 8;
    int sw = rsel & 7;
    int m0 = blockIdx.x * 128 + wv * 32;   // 32 nodes per wave

    f32x4 acc[2][4];
#pragma unroll
    for (int ms = 0; ms < 2; ++ms)
#pragma unroll
        for (int nt = 0; nt < 4; ++nt) acc[ms][nt] = (f32x4){0.f, 0.f, 0.f, 0.f};

#pragma unroll
    for (int ks = 0; ks < 4; ++ks) {
        short8 ahi[2], alo[2];
#pragma unroll
        for (int ms = 0; ms < 2; ++ms) {
            int row = m0 + ms * 16 + rsel; if (row >= NN) row = NN - 1;
            const float* hr = h + (size_t)row * HID + ks * 32 + koff;
            float4 p0 = *(const float4*)hr;
            float4 p1 = *(const float4*)(hr + 4);
            float vals[8] = {p0.x, p0.y, p0.z, p0.w, p1.x, p1.y, p1.z, p1.w};
#pragma unroll
            for (int e = 0; e < 8; ++e) {
                ushort hu = f2bf(vals[e]);
                ushort lu = f2bf(vals[e] - bf2f(hu));
                ahi[ms][e] = (short)hu; alo[ms][e] = (short)lu;
            }
        }
        int p = (ks * 4 + q16) ^ sw;
#pragma unroll
        for (int nt = 0; nt < 4; ++nt) {
            size_t bofs = (size_t)(nt * 16 + rsel) * HID + p * 8;
            short8 bh = *(const short8*)&bhi_sm[bofs];
            short8 bl = *(const short8*)&blo_sm[bofs];
#pragma unroll
            for (int ms = 0; ms < 2; ++ms) {
                acc[ms][nt] = __builtin_amdgcn_mfma_f32_16x16x32_bf16(ahi[ms], bh, acc[ms][nt], 0, 0, 0);
                acc[ms][nt] = __builtin_amdgcn_mfma_f32_16x16x32_bf16(alo[ms], bh, acc[ms][nt], 0, 0, 0);
                acc[ms][nt] = __builtin_amdgcn_mfma_f32_16x16x32_bf16(ahi[ms], bl, acc[ms][nt], 0, 0, 0);
            }
        }
    }

    // ---- epilogue: bias, row-softmax via 16-lane shfl tree, both outputs ----
    int col0 = lane & 15;
    float bias[4];
#pragma unroll
    for (int nt = 0; nt < 4; ++nt) bias[nt] = b2[nt * 16 + col0];
#pragma unroll
    for (int ms = 0; ms < 2; ++ms) {
#pragma unroll
        for (int r = 0; r < 4; ++r) {
            int node = m0 + ms * 16 + q16 * 4 + r;
            float v0 = acc[ms][0][r] + bias[0];
            float v1 = acc[ms][1][r] + bias[1];
            float v2 = acc[ms][2][r] + bias[2];
            float v3 = acc[ms][3][r] + bias[3];
            float m = fmaxf(fmaxf(v0, v1), fmaxf(v2, v3));
#pragma unroll
            for (int off = 8; off; off >>= 1) m = fmaxf(m, __shfl_xor(m, off));
            float s = __expf(v0 - m) + __expf(v1 - m) + __expf(v2 - m) + __expf(v3 - m);
#pragma unroll
            for (int off = 8; off; off >>= 1) s += __shfl_xor(s, off);
            float ls = m + __logf(s);
            if (node < NN) {
                out[(size_t)node * ODIM + 0 * 16 + col0] = v0 - ls;
                out[(size_t)node * ODIM + 1 * 16 + col0] = v1 - ls;
                out[(size_t)node * ODIM + 2 * 16 + col0] = v2 - ls;
                out[(size_t)node * ODIM + 3 * 16 + col0] = v3 - ls;
                size_t eb = (size_t)NN * ODIM + (size_t)node * ODIM;
                out[eb + 0 * 16 + col0] = v0;
                out[eb + 1 * 16 + col0] = v1;
                out[eb + 2 * 16 + col0] = v2;
                out[eb + 3 * 16 + col0] = v3;
            }
        }
    }
}

extern "C" void kernel_launch(void* const* d_in, const int* in_sizes, int n_in,
                              void* d_out, int out_size, void* d_ws, size_t ws_size,
                              hipStream_t stream) {
    const float* x    = (const float*)d_in[0];
    const int*   ei   = (const int*)d_in[1];
    const float* t1w  = (const float*)d_in[2];
    const float* t1b  = (const float*)d_in[3];
    const float* t2w  = (const float*)d_in[4];
    const float* t2b  = (const float*)d_in[5];
    const float* attl = (const float*)d_in[6];
    const float* attr = (const float*)d_in[7];
    float* out = (float*)d_out;

    const int* src = ei;
    const int* dst = ei + NE;

    char* ws = (char*)d_ws;
    size_t off = 0;
    auto alloc = [&](size_t bytes) { char* p = ws + off; off += (bytes + 255) & ~(size_t)255; return p; };
    float*  hA   = (float*)alloc((size_t)NN * HID * 4); // raw / h0
    float*  hB   = (float*)alloc((size_t)NN * HID * 4);
    float*  hC   = (float*)alloc((size_t)NN * HID * 4);
    ushort* wbf  = (ushort*)alloc((size_t)HID * IN_DIM * 2);
    int*    deg  = (int*)alloc((size_t)NN * 4);
    float*  dinv = (float*)alloc((size_t)NN * 4);
    int*    rowptr = (int*)alloc((size_t)(NN + 1) * 4);
    int*    cursor = (int*)alloc((size_t)NN * 4);
    int*    csr_src = (int*)alloc((size_t)NE * 4);
    int*    localScan = (int*)alloc((size_t)NN * 4);
    int*    blockSums = (int*)alloc((size_t)256 * 4);
    int*    blockOff  = (int*)alloc((size_t)256 * 4);
    float2* AD_A = (float2*)alloc((size_t)NN * 8);
    float*  AR_A = (float*)alloc((size_t)NN * 4);
    float2* AD_B = (float2*)alloc((size_t)NN * 8);
    float*  AR_B = (float*)alloc((size_t)NN * 4);
    (void)ws_size;

    hipMemsetAsync(deg, 0, (size_t)NN * 4, stream);

    dim3 blk(256);
    deg_kernel<<<(NE + 255) / 256, blk, 0, stream>>>(dst, deg);
    scanA_kernel<<<NBLK, blk, 0, stream>>>(deg, localScan, blockSums, dinv);
    scanB_kernel<<<1, blk, 0, stream>>>(blockSums, blockOff);
    scanC_kernel<<<NBLK, blk, 0, stream>>>(localScan, blockOff, rowptr, cursor);
    fill_kernel<<<(NE + 255) / 256, blk, 0, stream>>>(src, dst, cursor, csr_src);

    cvtw_kernel<<<(HID * IN_DIM + 255) / 256, blk, 0, stream>>>(t1w, wbf);
    // 196 blocks x 1024 threads, 256 rows each, B staged once per block
    gemm1_kernel<<<(NN + 255) / 256, dim3(1024), 0, stream>>>(x, wbf, t1b,
                                                              attl + 0 * HID, attr + 0 * HID,
                                                              dinv, hA, AD_A, AR_A);

    // L0: hA -> hB, epilogue computes layer-1 scalars into AD_B/AR_B
    agg_kernel<<<(NN + 3) / 4, blk, 0, stream>>>(hA, hA, hB, rowptr, csr_src, dinv,
                                                 AD_A, AR_A, attl + 1 * HID, attr + 1 * HID, AD_B, AR_B);
    // L1: hB -> hC, epilogue computes layer-2 scalars into AD_A/AR_A
    agg_kernel<<<(NN + 3) / 4, blk, 0, stream>>>(hB, hA, hC, rowptr, csr_src, dinv,
                                                 AD_B, AR_B, attl + 2 * HID, attr + 2 * HID, AD_A, AR_A);
    // L2: hC -> hB, no epilogue
    agg_kernel<<<(NN + 3) / 4, blk, 0, stream>>>(hC, hA, hB, rowptr, csr_src, dinv,
                                                 AD_A, AR_A, nullptr, nullptr, nullptr, nullptr);

    // 391 blocks x 256 threads, 128 nodes each (32 per wave)
    head_kernel<<<(NN + 127) / 128, blk, 0, stream>>>(hB, t2w, t2b, out);
}

// Round 7
// 377.982 us; speedup vs baseline: 1.3653x; 1.0951x over previous
//
#include <hip/hip_runtime.h>
#include <hip/hip_bf16.h>
#include <stdint.h>

#define NN 50000
#define NE 600000
#define IN_DIM 512
#define HID 128
#define ODIM 64
#define EPSV 0.1f
#define NBLK ((NN + 255) / 256)  // 196 scan blocks

typedef __attribute__((ext_vector_type(8))) short short8;
typedef __attribute__((ext_vector_type(4))) float f32x4;

__device__ __forceinline__ ushort f2bf(float f) {
    union { float f; uint32_t i; } v; v.f = f;
    uint32_t lsb = (v.i >> 16) & 1u;
    uint32_t r = v.i + 0x7fffu + lsb;
    return (ushort)(r >> 16);
}

__device__ __forceinline__ float bf2f(ushort u) {
    union { uint32_t i; float f; } v; v.i = ((uint32_t)u) << 16;
    return v.f;
}

// unpack a dword holding 2 bf16 (lo = even col, hi = odd col)
__device__ __forceinline__ float bflo(uint32_t u) {
    union { uint32_t i; float f; } v; v.i = u << 16; return v.f;
}
__device__ __forceinline__ float bfhi(uint32_t u) {
    union { uint32_t i; float f; } v; v.i = u & 0xffff0000u; return v.f;
}

__device__ __forceinline__ short8 pack8(float4 lo, float4 hi) {
    short8 r;
    r[0] = (short)f2bf(lo.x); r[1] = (short)f2bf(lo.y);
    r[2] = (short)f2bf(lo.z); r[3] = (short)f2bf(lo.w);
    r[4] = (short)f2bf(hi.x); r[5] = (short)f2bf(hi.y);
    r[6] = (short)f2bf(hi.z); r[7] = (short)f2bf(hi.w);
    return r;
}

// fast tanh: (e^2z - 1) / (e^2z + 1), clamped
__device__ __forceinline__ float fast_tanh(float z) {
    z = fminf(fmaxf(z, -15.f), 15.f);
    float t = __expf(2.f * z);
    return __fdividef(t - 1.f, t + 1.f);
}

// ---- degree count ----
__global__ __launch_bounds__(256) void deg_kernel(const int* __restrict__ dst, int* __restrict__ deg) {
    int e = blockIdx.x * 256 + threadIdx.x;
    if (e < NE) atomicAdd(&deg[dst[e]], 1);
}

// ---- scan phase A ----
__global__ __launch_bounds__(256) void scanA_kernel(const int* __restrict__ deg,
                                                    int* __restrict__ localScan,
                                                    int* __restrict__ blockSums,
                                                    float* __restrict__ dinv) {
    __shared__ int tmp[256];
    int t = threadIdx.x;
    int i = blockIdx.x * 256 + t;
    int v = (i < NN) ? deg[i] : 0;
    tmp[t] = v;
    __syncthreads();
    for (int off = 1; off < 256; off <<= 1) {
        int add = (t >= off) ? tmp[t - off] : 0;
        __syncthreads();
        tmp[t] += add;
        __syncthreads();
    }
    if (i < NN) {
        localScan[i] = tmp[t] - v;
        dinv[i] = (v > 0) ? (1.0f / sqrtf((float)v)) : 0.0f;
    }
    if (t == 255) blockSums[blockIdx.x] = tmp[255];
}

// ---- scan phase B ----
__global__ __launch_bounds__(256) void scanB_kernel(const int* __restrict__ blockSums,
                                                    int* __restrict__ blockOff) {
    __shared__ int tmp[256];
    int t = threadIdx.x;
    int v = (t < NBLK) ? blockSums[t] : 0;
    tmp[t] = v;
    __syncthreads();
    for (int off = 1; off < 256; off <<= 1) {
        int add = (t >= off) ? tmp[t - off] : 0;
        __syncthreads();
        tmp[t] += add;
        __syncthreads();
    }
    blockOff[t] = tmp[t] - v;
}

// ---- scan phase C ----
__global__ __launch_bounds__(256) void scanC_kernel(const int* __restrict__ localScan,
                                                    const int* __restrict__ blockOff,
                                                    int* __restrict__ rowptr,
                                                    int* __restrict__ cursor) {
    int i = blockIdx.x * 256 + threadIdx.x;
    if (i < NN) {
        int v = localScan[i] + blockOff[blockIdx.x];
        rowptr[i] = v;
        cursor[i] = v;
    }
    if (i == 0) rowptr[NN] = NE;
}

// ---- fill CSR ----
__global__ __launch_bounds__(256) void fill_kernel(const int* __restrict__ src, const int* __restrict__ dst,
                                                   int* __restrict__ cursor, int* __restrict__ csr_src) {
    int e = blockIdx.x * 256 + threadIdx.x;
    if (e < NE) {
        int d = dst[e];
        int slot = atomicAdd(&cursor[d], 1);
        csr_src[slot] = src[e];
    }
}

// ---- convert W1 fp32 -> bf16 ----
__global__ __launch_bounds__(256) void cvtw_kernel(const float* __restrict__ w, ushort* __restrict__ wbf) {
    int i = blockIdx.x * 256 + threadIdx.x;
    if (i < HID * IN_DIM) wbf[i] = f2bf(w[i]);
}

// ---- h0 = relu(x @ W1^T + b1), fused layer-0 attention scalars ----
// v5 (kept) + v7: also writes h0 as bf16 (gather operand for L0). f32 hA is
// kept as the exact eps*raw operand for all layers.
__global__ __launch_bounds__(1024, 4) void gemm1_kernel(const float* __restrict__ x,
                                                        const ushort* __restrict__ wbf,
                                                        const float* __restrict__ b,
                                                        const float* __restrict__ attl,
                                                        const float* __restrict__ attr,
                                                        const float* __restrict__ dinv,
                                                        float* __restrict__ h,
                                                        ushort* __restrict__ hb,
                                                        float2* __restrict__ AD,
                                                        float* __restrict__ AR) {
    __shared__ __attribute__((aligned(16))) ushort b_sm[HID * IN_DIM]; // 128 KB
    int t = threadIdx.x;
    int wv = __builtin_amdgcn_readfirstlane(t >> 6);   // 0..15
    int lane = t & 63;
    int m0 = blockIdx.x * 256;

    // ---- stage B: 8 rounds x 1024 threads x 16B granule, row-XOR swizzle ----
    {
        uint4 bg[8];
#pragma unroll
        for (int rnd = 0; rnd < 8; ++rnd)
            bg[rnd] = *(const uint4*)(wbf + (size_t)(rnd * 1024 + t) * 8);
#pragma unroll
        for (int rnd = 0; rnd < 8; ++rnd) {
            int G = rnd * 1024 + t;            // global granule 0..8191
            int row = G >> 6;                  // B row 0..127
            int g = G & 63;                    // granule within row
            *(uint4*)&b_sm[(size_t)((row << 6) | (g ^ (row & 7))) * 8] = bg[rnd];
        }
    }
    __syncthreads();

    // fragment map
    int rsel = lane & 15;          // A row within stripe / B row select
    int koff = (lane >> 4) * 8;    // K sub-offset (floats / ushorts)
    int sw = rsel & 7;             // B row swizzle key
    int qg = koff >> 3;            // quarter-granule index 0..3
    int row = m0 + wv * 16 + rsel; if (row >= NN) row = NN - 1;
    const float* xr = x + (size_t)row * IN_DIM + koff;

    f32x4 acc[8];
#pragma unroll
    for (int tt = 0; tt < 8; ++tt) acc[tt] = (f32x4){0.f, 0.f, 0.f, 0.f};

    // depth-2 prefetch: two K-steps (2 x 8 floats/lane) in flight
    float4 c0lo = *(const float4*)(xr);
    float4 c0hi = *(const float4*)(xr + 4);
    float4 c1lo = *(const float4*)(xr + 32);
    float4 c1hi = *(const float4*)(xr + 36);

#pragma unroll
    for (int ks = 0; ks < 16; ks += 2) {
        float4 n0lo, n0hi, n1lo, n1hi;
        bool more = (ks + 2 < 16);
        if (more) {
            n0lo = *(const float4*)(xr + (ks + 2) * 32);
            n0hi = *(const float4*)(xr + (ks + 2) * 32 + 4);
            n1lo = *(const float4*)(xr + (ks + 3) * 32);
            n1hi = *(const float4*)(xr + (ks + 3) * 32 + 4);
        }
        short8 a0 = pack8(c0lo, c0hi);
#pragma unroll
        for (int tt = 0; tt < 8; ++tt) {
            int rb = tt * 16 + rsel;
            short8 bf = *(const short8*)&b_sm[(size_t)(rb << 9) + (size_t)(((ks * 4 + qg) ^ sw) << 3)];
            acc[tt] = __builtin_amdgcn_mfma_f32_16x16x32_bf16(a0, bf, acc[tt], 0, 0, 0);
        }
        short8 a1 = pack8(c1lo, c1hi);
#pragma unroll
        for (int tt = 0; tt < 8; ++tt) {
            int rb = tt * 16 + rsel;
            short8 bf = *(const short8*)&b_sm[(size_t)(rb << 9) + (size_t)((((ks + 1) * 4 + qg) ^ sw) << 3)];
            acc[tt] = __builtin_amdgcn_mfma_f32_16x16x32_bf16(a1, bf, acc[tt], 0, 0, 0);
        }
        if (more) { c0lo = n0lo; c0hi = n0hi; c1lo = n1lo; c1hi = n1hi; }
    }

    // epilogue: bias + relu + stores (f32 + bf16) + fused layer-0 att scalars
    int rbase = (lane >> 4) * 4;
    int col0 = lane & 15;
    float alv[8], arv[8], bias[8];
#pragma unroll
    for (int tt = 0; tt < 8; ++tt) {
        alv[tt]  = attl[tt * 16 + col0];
        arv[tt]  = attr[tt * 16 + col0];
        bias[tt] = b[tt * 16 + col0];
    }
#pragma unroll
    for (int r = 0; r < 4; ++r) {
        int rrow = m0 + wv * 16 + rbase + r;
        float p = 0.f, q = 0.f;
#pragma unroll
        for (int tt = 0; tt < 8; ++tt) {
            float v = acc[tt][r] + bias[tt];
            v = v > 0.f ? v : 0.f;
            if (rrow < NN) {
                h[(size_t)rrow * HID + tt * 16 + col0] = v;
                hb[(size_t)rrow * HID + tt * 16 + col0] = f2bf(v);
            }
            p += v * alv[tt];
            q += v * arv[tt];
        }
#pragma unroll
        for (int off = 8; off; off >>= 1) { p += __shfl_xor(p, off); q += __shfl_xor(q, off); }
        if (col0 == 0 && rrow < NN) {
            float2 vv; vv.x = p; vv.y = dinv[rrow];
            AD[rrow] = vv;
            AR[rrow] = q;
        }
    }
}

// ---- FAConv aggregation: wave per dst node, bf16 gather (halved traffic) ----
// agg is AT the vector-path byte cap (~6.3 TB/s): 366 MB/layer -> 58 us.
// bf16 h rows (256 B) cut it to ~200 MB -> ~32 us. f32 kept for: raw term
// (hA), accumulators, and AD/AR epilogue scalars.
__global__ __launch_bounds__(256) void agg_kernel(const ushort* __restrict__ hb,
                                                  const float* __restrict__ raw,
                                                  ushort* __restrict__ hnb,
                                                  const int* __restrict__ rowptr,
                                                  const int* __restrict__ csr_src,
                                                  const float* __restrict__ dinv,
                                                  const float2* __restrict__ AD,
                                                  const float* __restrict__ AR,
                                                  const float* __restrict__ attl_next,
                                                  const float* __restrict__ attr_next,
                                                  float2* __restrict__ ADout,
                                                  float* __restrict__ ARout) {
    int wv = __builtin_amdgcn_readfirstlane(threadIdx.x >> 6);
    int lane = threadIdx.x & 63;
    int d = blockIdx.x * 4 + wv;
    if (d >= NN) return;
    const uint32_t* h4 = (const uint32_t*)hb;   // 2 bf16 per dword, 64 dwords/row
    float ar_d = AR[d];
    float dinv_d = dinv[d];
    float2 rawd = ((const float2*)raw)[(size_t)d * 64 + lane];
    float accx = EPSV * rawd.x, accy = EPSV * rawd.y;
    int e = rowptr[d], e1 = rowptr[d + 1];
    // ---- 8-deep: 1 broadcast index load + 8 concurrent 256B row loads ----
    for (; e + 8 <= e1; e += 8) {
        int sv = csr_src[e + (lane & 7)];
        int s0 = __builtin_amdgcn_readfirstlane(__shfl(sv, 0));
        int s1 = __builtin_amdgcn_readfirstlane(__shfl(sv, 1));
        int s2 = __builtin_amdgcn_readfirstlane(__shfl(sv, 2));
        int s3 = __builtin_amdgcn_readfirstlane(__shfl(sv, 3));
        int s4 = __builtin_amdgcn_readfirstlane(__shfl(sv, 4));
        int s5 = __builtin_amdgcn_readfirstlane(__shfl(sv, 5));
        int s6 = __builtin_amdgcn_readfirstlane(__shfl(sv, 6));
        int s7 = __builtin_amdgcn_readfirstlane(__shfl(sv, 7));
        float2 ad0 = AD[s0], ad1 = AD[s1], ad2 = AD[s2], ad3 = AD[s3];
        float2 ad4 = AD[s4], ad5 = AD[s5], ad6 = AD[s6], ad7 = AD[s7];
        uint32_t u0 = h4[(size_t)s0 * 64 + lane];
        uint32_t u1 = h4[(size_t)s1 * 64 + lane];
        uint32_t u2 = h4[(size_t)s2 * 64 + lane];
        uint32_t u3 = h4[(size_t)s3 * 64 + lane];
        uint32_t u4 = h4[(size_t)s4 * 64 + lane];
        uint32_t u5 = h4[(size_t)s5 * 64 + lane];
        uint32_t u6 = h4[(size_t)s6 * 64 + lane];
        uint32_t u7 = h4[(size_t)s7 * 64 + lane];
        float w0 = fast_tanh(ad0.x + ar_d) * ad0.y * dinv_d;
        float w1 = fast_tanh(ad1.x + ar_d) * ad1.y * dinv_d;
        float w2 = fast_tanh(ad2.x + ar_d) * ad2.y * dinv_d;
        float w3 = fast_tanh(ad3.x + ar_d) * ad3.y * dinv_d;
        float w4 = fast_tanh(ad4.x + ar_d) * ad4.y * dinv_d;
        float w5 = fast_tanh(ad5.x + ar_d) * ad5.y * dinv_d;
        float w6 = fast_tanh(ad6.x + ar_d) * ad6.y * dinv_d;
        float w7 = fast_tanh(ad7.x + ar_d) * ad7.y * dinv_d;
        accx += w0 * bflo(u0) + w1 * bflo(u1) + w2 * bflo(u2) + w3 * bflo(u3);
        accy += w0 * bfhi(u0) + w1 * bfhi(u1) + w2 * bfhi(u2) + w3 * bfhi(u3);
        accx += w4 * bflo(u4) + w5 * bflo(u5) + w6 * bflo(u6) + w7 * bflo(u7);
        accy += w4 * bfhi(u4) + w5 * bfhi(u5) + w6 * bfhi(u6) + w7 * bfhi(u7);
    }
    for (; e + 4 <= e1; e += 4) {
        int sv = csr_src[e + (lane & 3)];
        int s0 = __builtin_amdgcn_readfirstlane(__shfl(sv, 0));
        int s1 = __builtin_amdgcn_readfirstlane(__shfl(sv, 1));
        int s2 = __builtin_amdgcn_readfirstlane(__shfl(sv, 2));
        int s3 = __builtin_amdgcn_readfirstlane(__shfl(sv, 3));
        float2 ad0 = AD[s0], ad1 = AD[s1], ad2 = AD[s2], ad3 = AD[s3];
        uint32_t u0 = h4[(size_t)s0 * 64 + lane];
        uint32_t u1 = h4[(size_t)s1 * 64 + lane];
        uint32_t u2 = h4[(size_t)s2 * 64 + lane];
        uint32_t u3 = h4[(size_t)s3 * 64 + lane];
        float w0 = fast_tanh(ad0.x + ar_d) * ad0.y * dinv_d;
        float w1 = fast_tanh(ad1.x + ar_d) * ad1.y * dinv_d;
        float w2 = fast_tanh(ad2.x + ar_d) * ad2.y * dinv_d;
        float w3 = fast_tanh(ad3.x + ar_d) * ad3.y * dinv_d;
        accx += w0 * bflo(u0) + w1 * bflo(u1) + w2 * bflo(u2) + w3 * bflo(u3);
        accy += w0 * bfhi(u0) + w1 * bfhi(u1) + w2 * bfhi(u2) + w3 * bfhi(u3);
    }
    for (; e < e1; ++e) {
        int s = __builtin_amdgcn_readfirstlane(csr_src[e]);
        float2 ad = AD[s];
        uint32_t u = h4[(size_t)s * 64 + lane];
        float w = fast_tanh(ad.x + ar_d) * ad.y * dinv_d;
        accx += w * bflo(u);
        accy += w * bfhi(u);
    }
    ((uint32_t*)hnb)[(size_t)d * 64 + lane] =
        (uint32_t)f2bf(accx) | ((uint32_t)f2bf(accy) << 16);
    if (attl_next) {
        float al0 = attl_next[2 * lane], al1 = attl_next[2 * lane + 1];
        float ar0 = attr_next[2 * lane], ar1 = attr_next[2 * lane + 1];
        float p = accx * al0 + accy * al1;
        float q = accx * ar0 + accy * ar1;
#pragma unroll
        for (int off = 32; off; off >>= 1) { p += __shfl_xor(p, off); q += __shfl_xor(q, off); }
        if (lane == 0) {
            float2 v; v.x = p; v.y = dinv_d;
            ADout[d] = v;
            ARout[d] = q;
        }
    }
}

// ---- head: emb = h @ W2^T + b2; out0 = log_softmax(emb); out1 = emb ----
// v7: A-operand is exactly bf16 now (hb), so the split reduces to 2 MFMAs:
// a*bh + a*bl (w2 hi/lo). Error only from w2 split (~2^-17) + f32 accum.
__global__ __launch_bounds__(256) void head_kernel(const ushort* __restrict__ hb,
                                                   const float* __restrict__ w2,
                                                   const float* __restrict__ b2,
                                                   float* __restrict__ out) {
    __shared__ __attribute__((aligned(16))) ushort bhi_sm[ODIM * HID]; // 16 KB
    __shared__ __attribute__((aligned(16))) ushort blo_sm[ODIM * HID]; // 16 KB
    int t = threadIdx.x;
    int wv = __builtin_amdgcn_readfirstlane(t >> 6);
    int lane = t & 63;

    // ---- stage w2 -> hi/lo bf16, 16B-granule XOR swizzle (key = row&7) ----
    {
        int j = t >> 2;                 // output col 0..63
        int k0 = (t & 3) * 32;          // k chunk
        const float* wr = w2 + (size_t)j * HID + k0;
#pragma unroll
        for (int gg = 0; gg < 4; ++gg) {
            float4 a4 = *(const float4*)(wr + gg * 8);
            float4 b4 = *(const float4*)(wr + gg * 8 + 4);
            float vals[8] = {a4.x, a4.y, a4.z, a4.w, b4.x, b4.y, b4.z, b4.w};
            short8 vhi, vlo;
#pragma unroll
            for (int e = 0; e < 8; ++e) {
                ushort hu = f2bf(vals[e]);
                ushort lu = f2bf(vals[e] - bf2f(hu));
                vhi[e] = (short)hu; vlo[e] = (short)lu;
            }
            int g = (t & 3) * 4 + gg;          // granule 0..15
            int p = g ^ (j & 7);
            *(short8*)&bhi_sm[(size_t)j * HID + p * 8] = vhi;
            *(short8*)&blo_sm[(size_t)j * HID + p * 8] = vlo;
        }
    }
    __syncthreads();

    int rsel = lane & 15;
    int q16 = lane >> 4;            // 0..3
    int koff = q16 * 8;
    int sw = rsel & 7;
    int m0 = blockIdx.x * 128 + wv * 32;   // 32 nodes per wave

    f32x4 acc[2][4];
#pragma unroll
    for (int ms = 0; ms < 2; ++ms)
#pragma unroll
        for (int nt = 0; nt < 4; ++nt) acc[ms][nt] = (f32x4){0.f, 0.f, 0.f, 0.f};

#pragma unroll
    for (int ks = 0; ks < 4; ++ks) {
        short8 a[2];
#pragma unroll
        for (int ms = 0; ms < 2; ++ms) {
            int row = m0 + ms * 16 + rsel; if (row >= NN) row = NN - 1;
            a[ms] = *(const short8*)(hb + (size_t)row * HID + ks * 32 + koff);
        }
        int p = (ks * 4 + q16) ^ sw;
#pragma unroll
        for (int nt = 0; nt < 4; ++nt) {
            size_t bofs = (size_t)(nt * 16 + rsel) * HID + p * 8;
            short8 bh = *(const short8*)&bhi_sm[bofs];
            short8 bl = *(const short8*)&blo_sm[bofs];
#pragma unroll
            for (int ms = 0; ms < 2; ++ms) {
                acc[ms][nt] = __builtin_amdgcn_mfma_f32_16x16x32_bf16(a[ms], bh, acc[ms][nt], 0, 0, 0);
                acc[ms][nt] = __builtin_amdgcn_mfma_f32_16x16x32_bf16(a[ms], bl, acc[ms][nt], 0, 0, 0);
            }
        }
    }

    // ---- epilogue: bias, row-softmax via 16-lane shfl tree, both outputs ----
    int col0 = lane & 15;
    float bias[4];
#pragma unroll
    for (int nt = 0; nt < 4; ++nt) bias[nt] = b2[nt * 16 + col0];
#pragma unroll
    for (int ms = 0; ms < 2; ++ms) {
#pragma unroll
        for (int r = 0; r < 4; ++r) {
            int node = m0 + ms * 16 + q16 * 4 + r;
            float v0 = acc[ms][0][r] + bias[0];
            float v1 = acc[ms][1][r] + bias[1];
            float v2 = acc[ms][2][r] + bias[2];
            float v3 = acc[ms][3][r] + bias[3];
            float m = fmaxf(fmaxf(v0, v1), fmaxf(v2, v3));
#pragma unroll
            for (int off = 8; off; off >>= 1) m = fmaxf(m, __shfl_xor(m, off));
            float s = __expf(v0 - m) + __expf(v1 - m) + __expf(v2 - m) + __expf(v3 - m);
#pragma unroll
            for (int off = 8; off; off >>= 1) s += __shfl_xor(s, off);
            float ls = m + __logf(s);
            if (node < NN) {
                out[(size_t)node * ODIM + 0 * 16 + col0] = v0 - ls;
                out[(size_t)node * ODIM + 1 * 16 + col0] = v1 - ls;
                out[(size_t)node * ODIM + 2 * 16 + col0] = v2 - ls;
                out[(size_t)node * ODIM + 3 * 16 + col0] = v3 - ls;
                size_t eb = (size_t)NN * ODIM + (size_t)node * ODIM;
                out[eb + 0 * 16 + col0] = v0;
                out[eb + 1 * 16 + col0] = v1;
                out[eb + 2 * 16 + col0] = v2;
                out[eb + 3 * 16 + col0] = v3;
            }
        }
    }
}

extern "C" void kernel_launch(void* const* d_in, const int* in_sizes, int n_in,
                              void* d_out, int out_size, void* d_ws, size_t ws_size,
                              hipStream_t stream) {
    const float* x    = (const float*)d_in[0];
    const int*   ei   = (const int*)d_in[1];
    const float* t1w  = (const float*)d_in[2];
    const float* t1b  = (const float*)d_in[3];
    const float* t2w  = (const float*)d_in[4];
    const float* t2b  = (const float*)d_in[5];
    const float* attl = (const float*)d_in[6];
    const float* attr = (const float*)d_in[7];
    float* out = (float*)d_out;

    const int* src = ei;
    const int* dst = ei + NE;

    char* ws = (char*)d_ws;
    size_t off = 0;
    auto alloc = [&](size_t bytes) { char* p = ws + off; off += (bytes + 255) & ~(size_t)255; return p; };
    float*  hA   = (float*)alloc((size_t)NN * HID * 4);   // f32 raw (h0)
    ushort* h0b  = (ushort*)alloc((size_t)NN * HID * 2);  // bf16 h0
    ushort* h1b  = (ushort*)alloc((size_t)NN * HID * 2);
    ushort* h2b  = (ushort*)alloc((size_t)NN * HID * 2);
    ushort* h3b  = (ushort*)alloc((size_t)NN * HID * 2);
    ushort* wbf  = (ushort*)alloc((size_t)HID * IN_DIM * 2);
    int*    deg  = (int*)alloc((size_t)NN * 4);
    float*  dinv = (float*)alloc((size_t)NN * 4);
    int*    rowptr = (int*)alloc((size_t)(NN + 1) * 4);
    int*    cursor = (int*)alloc((size_t)NN * 4);
    int*    csr_src = (int*)alloc((size_t)NE * 4);
    int*    localScan = (int*)alloc((size_t)NN * 4);
    int*    blockSums = (int*)alloc((size_t)256 * 4);
    int*    blockOff  = (int*)alloc((size_t)256 * 4);
    float2* AD_A = (float2*)alloc((size_t)NN * 8);
    float*  AR_A = (float*)alloc((size_t)NN * 4);
    float2* AD_B = (float2*)alloc((size_t)NN * 8);
    float*  AR_B = (float*)alloc((size_t)NN * 4);
    (void)ws_size;

    hipMemsetAsync(deg, 0, (size_t)NN * 4, stream);

    dim3 blk(256);
    deg_kernel<<<(NE + 255) / 256, blk, 0, stream>>>(dst, deg);
    scanA_kernel<<<NBLK, blk, 0, stream>>>(deg, localScan, blockSums, dinv);
    scanB_kernel<<<1, blk, 0, stream>>>(blockSums, blockOff);
    scanC_kernel<<<NBLK, blk, 0, stream>>>(localScan, blockOff, rowptr, cursor);
    fill_kernel<<<(NE + 255) / 256, blk, 0, stream>>>(src, dst, cursor, csr_src);

    cvtw_kernel<<<(HID * IN_DIM + 255) / 256, blk, 0, stream>>>(t1w, wbf);
    // 196 blocks x 1024 threads, 256 rows each, B staged once per block
    gemm1_kernel<<<(NN + 255) / 256, dim3(1024), 0, stream>>>(x, wbf, t1b,
                                                              attl + 0 * HID, attr + 0 * HID,
                                                              dinv, hA, h0b, AD_A, AR_A);

    // L0: h0b -> h1b, epilogue computes layer-1 scalars into AD_B/AR_B
    agg_kernel<<<(NN + 3) / 4, blk, 0, stream>>>(h0b, hA, h1b, rowptr, csr_src, dinv,
                                                 AD_A, AR_A, attl + 1 * HID, attr + 1 * HID, AD_B, AR_B);
    // L1: h1b -> h2b, epilogue computes layer-2 scalars into AD_A/AR_A
    agg_kernel<<<(NN + 3) / 4, blk, 0, stream>>>(h1b, hA, h2b, rowptr, csr_src, dinv,
                                                 AD_B, AR_B, attl + 2 * HID, attr + 2 * HID, AD_A, AR_A);
    // L2: h2b -> h3b, no epilogue
    agg_kernel<<<(NN + 3) / 4, blk, 0, stream>>>(h2b, hA, h3b, rowptr, csr_src, dinv,
                                                 AD_A, AR_A, nullptr, nullptr, nullptr, nullptr);

    // 391 blocks x 256 threads, 128 nodes each (32 per wave)
    head_kernel<<<(NN + 127) / 128, blk, 0, stream>>>(h3b, t2w, t2b, out);
}

// Round 8
// 371.881 us; speedup vs baseline: 1.3877x; 1.0164x over previous
//
#include <hip/hip_runtime.h>
#include <hip/hip_bf16.h>
#include <stdint.h>

#define NN 50000
#define NE 600000
#define IN_DIM 512
#define HID 128
#define ODIM 64
#define EPSV 0.1f
#define NBLK ((NN + 255) / 256)  // 196 scan blocks

typedef __attribute__((ext_vector_type(8))) short short8;
typedef __attribute__((ext_vector_type(4))) float f32x4;

__device__ __forceinline__ ushort f2bf(float f) {
    union { float f; uint32_t i; } v; v.f = f;
    uint32_t lsb = (v.i >> 16) & 1u;
    uint32_t r = v.i + 0x7fffu + lsb;
    return (ushort)(r >> 16);
}

__device__ __forceinline__ float bf2f(ushort u) {
    union { uint32_t i; float f; } v; v.i = ((uint32_t)u) << 16;
    return v.f;
}

// unpack a dword holding 2 bf16 (lo = even col, hi = odd col)
__device__ __forceinline__ float bflo(uint32_t u) {
    union { uint32_t i; float f; } v; v.i = u << 16; return v.f;
}
__device__ __forceinline__ float bfhi(uint32_t u) {
    union { uint32_t i; float f; } v; v.i = u & 0xffff0000u; return v.f;
}

__device__ __forceinline__ short8 pack8(float4 lo, float4 hi) {
    short8 r;
    r[0] = (short)f2bf(lo.x); r[1] = (short)f2bf(lo.y);
    r[2] = (short)f2bf(lo.z); r[3] = (short)f2bf(lo.w);
    r[4] = (short)f2bf(hi.x); r[5] = (short)f2bf(hi.y);
    r[6] = (short)f2bf(hi.z); r[7] = (short)f2bf(hi.w);
    return r;
}

// fast tanh: (e^2z - 1) / (e^2z + 1), clamped
__device__ __forceinline__ float fast_tanh(float z) {
    z = fminf(fmaxf(z, -15.f), 15.f);
    float t = __expf(2.f * z);
    return __fdividef(t - 1.f, t + 1.f);
}

// ---- degree count ----
__global__ __launch_bounds__(256) void deg_kernel(const int* __restrict__ dst, int* __restrict__ deg) {
    int e = blockIdx.x * 256 + threadIdx.x;
    if (e < NE) atomicAdd(&deg[dst[e]], 1);
}

// ---- scan phase A ----
__global__ __launch_bounds__(256) void scanA_kernel(const int* __restrict__ deg,
                                                    int* __restrict__ localScan,
                                                    int* __restrict__ blockSums,
                                                    float* __restrict__ dinv) {
    __shared__ int tmp[256];
    int t = threadIdx.x;
    int i = blockIdx.x * 256 + t;
    int v = (i < NN) ? deg[i] : 0;
    tmp[t] = v;
    __syncthreads();
    for (int off = 1; off < 256; off <<= 1) {
        int add = (t >= off) ? tmp[t - off] : 0;
        __syncthreads();
        tmp[t] += add;
        __syncthreads();
    }
    if (i < NN) {
        localScan[i] = tmp[t] - v;
        dinv[i] = (v > 0) ? (1.0f / sqrtf((float)v)) : 0.0f;
    }
    if (t == 255) blockSums[blockIdx.x] = tmp[255];
}

// ---- scan phase B ----
__global__ __launch_bounds__(256) void scanB_kernel(const int* __restrict__ blockSums,
                                                    int* __restrict__ blockOff) {
    __shared__ int tmp[256];
    int t = threadIdx.x;
    int v = (t < NBLK) ? blockSums[t] : 0;
    tmp[t] = v;
    __syncthreads();
    for (int off = 1; off < 256; off <<= 1) {
        int add = (t >= off) ? tmp[t - off] : 0;
        __syncthreads();
        tmp[t] += add;
        __syncthreads();
    }
    blockOff[t] = tmp[t] - v;
}

// ---- scan phase C ----
__global__ __launch_bounds__(256) void scanC_kernel(const int* __restrict__ localScan,
                                                    const int* __restrict__ blockOff,
                                                    int* __restrict__ rowptr,
                                                    int* __restrict__ cursor) {
    int i = blockIdx.x * 256 + threadIdx.x;
    if (i < NN) {
        int v = localScan[i] + blockOff[blockIdx.x];
        rowptr[i] = v;
        cursor[i] = v;
    }
    if (i == 0) rowptr[NN] = NE;
}

// ---- fill CSR ----
__global__ __launch_bounds__(256) void fill_kernel(const int* __restrict__ src, const int* __restrict__ dst,
                                                   int* __restrict__ cursor, int* __restrict__ csr_src) {
    int e = blockIdx.x * 256 + threadIdx.x;
    if (e < NE) {
        int d = dst[e];
        int slot = atomicAdd(&cursor[d], 1);
        csr_src[slot] = src[e];
    }
}

// ---- convert W1 fp32 -> bf16 ----
__global__ __launch_bounds__(256) void cvtw_kernel(const float* __restrict__ w, ushort* __restrict__ wbf) {
    int i = blockIdx.x * 256 + threadIdx.x;
    if (i < HID * IN_DIM) wbf[i] = f2bf(w[i]);
}

// ---- h0 = relu(x @ W1^T + b1), fused layer-0 attention scalars ----
// v5 (kept) + v8: only the bf16 h0 is written now (f32 raw dropped -- the
// eps*raw term uses bf16 h0; error 0.1*2^-9*|h0| ~ 2e-4, far under the
// 0.03125 bf16-gemm floor). AD/AR still from f32 accumulators.
__global__ __launch_bounds__(1024, 4) void gemm1_kernel(const float* __restrict__ x,
                                                        const ushort* __restrict__ wbf,
                                                        const float* __restrict__ b,
                                                        const float* __restrict__ attl,
                                                        const float* __restrict__ attr,
                                                        const float* __restrict__ dinv,
                                                        ushort* __restrict__ hb,
                                                        float2* __restrict__ AD,
                                                        float* __restrict__ AR) {
    __shared__ __attribute__((aligned(16))) ushort b_sm[HID * IN_DIM]; // 128 KB
    int t = threadIdx.x;
    int wv = __builtin_amdgcn_readfirstlane(t >> 6);   // 0..15
    int lane = t & 63;
    int m0 = blockIdx.x * 256;

    // ---- stage B: 8 rounds x 1024 threads x 16B granule, row-XOR swizzle ----
    {
        uint4 bg[8];
#pragma unroll
        for (int rnd = 0; rnd < 8; ++rnd)
            bg[rnd] = *(const uint4*)(wbf + (size_t)(rnd * 1024 + t) * 8);
#pragma unroll
        for (int rnd = 0; rnd < 8; ++rnd) {
            int G = rnd * 1024 + t;            // global granule 0..8191
            int row = G >> 6;                  // B row 0..127
            int g = G & 63;                    // granule within row
            *(uint4*)&b_sm[(size_t)((row << 6) | (g ^ (row & 7))) * 8] = bg[rnd];
        }
    }
    __syncthreads();

    // fragment map
    int rsel = lane & 15;          // A row within stripe / B row select
    int koff = (lane >> 4) * 8;    // K sub-offset (floats / ushorts)
    int sw = rsel & 7;             // B row swizzle key
    int qg = koff >> 3;            // quarter-granule index 0..3
    int row = m0 + wv * 16 + rsel; if (row >= NN) row = NN - 1;
    const float* xr = x + (size_t)row * IN_DIM + koff;

    f32x4 acc[8];
#pragma unroll
    for (int tt = 0; tt < 8; ++tt) acc[tt] = (f32x4){0.f, 0.f, 0.f, 0.f};

    // depth-2 prefetch: two K-steps (2 x 8 floats/lane) in flight
    float4 c0lo = *(const float4*)(xr);
    float4 c0hi = *(const float4*)(xr + 4);
    float4 c1lo = *(const float4*)(xr + 32);
    float4 c1hi = *(const float4*)(xr + 36);

#pragma unroll
    for (int ks = 0; ks < 16; ks += 2) {
        float4 n0lo, n0hi, n1lo, n1hi;
        bool more = (ks + 2 < 16);
        if (more) {
            n0lo = *(const float4*)(xr + (ks + 2) * 32);
            n0hi = *(const float4*)(xr + (ks + 2) * 32 + 4);
            n1lo = *(const float4*)(xr + (ks + 3) * 32);
            n1hi = *(const float4*)(xr + (ks + 3) * 32 + 4);
        }
        short8 a0 = pack8(c0lo, c0hi);
#pragma unroll
        for (int tt = 0; tt < 8; ++tt) {
            int rb = tt * 16 + rsel;
            short8 bf = *(const short8*)&b_sm[(size_t)(rb << 9) + (size_t)(((ks * 4 + qg) ^ sw) << 3)];
            acc[tt] = __builtin_amdgcn_mfma_f32_16x16x32_bf16(a0, bf, acc[tt], 0, 0, 0);
        }
        short8 a1 = pack8(c1lo, c1hi);
#pragma unroll
        for (int tt = 0; tt < 8; ++tt) {
            int rb = tt * 16 + rsel;
            short8 bf = *(const short8*)&b_sm[(size_t)(rb << 9) + (size_t)((((ks + 1) * 4 + qg) ^ sw) << 3)];
            acc[tt] = __builtin_amdgcn_mfma_f32_16x16x32_bf16(a1, bf, acc[tt], 0, 0, 0);
        }
        if (more) { c0lo = n0lo; c0hi = n0hi; c1lo = n1lo; c1hi = n1hi; }
    }

    // epilogue: bias + relu + bf16 store + fused layer-0 att scalars
    int rbase = (lane >> 4) * 4;
    int col0 = lane & 15;
    float alv[8], arv[8], bias[8];
#pragma unroll
    for (int tt = 0; tt < 8; ++tt) {
        alv[tt]  = attl[tt * 16 + col0];
        arv[tt]  = attr[tt * 16 + col0];
        bias[tt] = b[tt * 16 + col0];
    }
#pragma unroll
    for (int r = 0; r < 4; ++r) {
        int rrow = m0 + wv * 16 + rbase + r;
        float p = 0.f, q = 0.f;
#pragma unroll
        for (int tt = 0; tt < 8; ++tt) {
            float v = acc[tt][r] + bias[tt];
            v = v > 0.f ? v : 0.f;
            if (rrow < NN) hb[(size_t)rrow * HID + tt * 16 + col0] = f2bf(v);
            p += v * alv[tt];
            q += v * arv[tt];
        }
#pragma unroll
        for (int off = 8; off; off >>= 1) { p += __shfl_xor(p, off); q += __shfl_xor(q, off); }
        if (col0 == 0 && rrow < NN) {
            float2 vv; vv.x = p; vv.y = dinv[rrow];
            AD[rrow] = vv;
            AR[rrow] = q;
        }
    }
}

// ---- FAConv aggregation: wave per dst node ----
// v8: edge indices preloaded 64-at-a-time into a register (ONE vmem op per
// <=64 edges, ~5x avg degree) and extracted with v_readlane -> the idx-load
// -> row-load memory dependency disappears from every 8-edge chunk and from
// every tail edge. raw is bf16 (h0b). AD loads stay scalar (SGPR index).
__global__ __launch_bounds__(256) void agg_kernel(const ushort* __restrict__ hb,
                                                  const ushort* __restrict__ rawb,
                                                  ushort* __restrict__ hnb,
                                                  const int* __restrict__ rowptr,
                                                  const int* __restrict__ csr_src,
                                                  const float* __restrict__ dinv,
                                                  const float2* __restrict__ AD,
                                                  const float* __restrict__ AR,
                                                  const float* __restrict__ attl_next,
                                                  const float* __restrict__ attr_next,
                                                  float2* __restrict__ ADout,
                                                  float* __restrict__ ARout) {
    int wv = __builtin_amdgcn_readfirstlane(threadIdx.x >> 6);
    int lane = threadIdx.x & 63;
    int d = blockIdx.x * 4 + wv;
    if (d >= NN) return;
    const uint32_t* h4 = (const uint32_t*)hb;   // 2 bf16 per dword, 64 dwords/row
    float ar_d = AR[d];
    float dinv_d = dinv[d];
    uint32_t rawd = ((const uint32_t*)rawb)[(size_t)d * 64 + lane];
    float accx = EPSV * bflo(rawd), accy = EPSV * bfhi(rawd);
    int e0 = rowptr[d], e1 = rowptr[d + 1];
    for (int base = e0; base < e1; base += 64) {
        int cnt = e1 - base; if (cnt > 64) cnt = 64;
        int gi = base + lane; if (gi > NE - 1) gi = NE - 1;
        int myidx = csr_src[gi];               // one load covers 64 edges
        int c = 0;
        for (; c + 8 <= cnt; c += 8) {
            int s0 = __builtin_amdgcn_readlane(myidx, c + 0);
            int s1 = __builtin_amdgcn_readlane(myidx, c + 1);
            int s2 = __builtin_amdgcn_readlane(myidx, c + 2);
            int s3 = __builtin_amdgcn_readlane(myidx, c + 3);
            int s4 = __builtin_amdgcn_readlane(myidx, c + 4);
            int s5 = __builtin_amdgcn_readlane(myidx, c + 5);
            int s6 = __builtin_amdgcn_readlane(myidx, c + 6);
            int s7 = __builtin_amdgcn_readlane(myidx, c + 7);
            float2 ad0 = AD[s0], ad1 = AD[s1], ad2 = AD[s2], ad3 = AD[s3];
            float2 ad4 = AD[s4], ad5 = AD[s5], ad6 = AD[s6], ad7 = AD[s7];
            uint32_t u0 = h4[(size_t)s0 * 64 + lane];
            uint32_t u1 = h4[(size_t)s1 * 64 + lane];
            uint32_t u2 = h4[(size_t)s2 * 64 + lane];
            uint32_t u3 = h4[(size_t)s3 * 64 + lane];
            uint32_t u4 = h4[(size_t)s4 * 64 + lane];
            uint32_t u5 = h4[(size_t)s5 * 64 + lane];
            uint32_t u6 = h4[(size_t)s6 * 64 + lane];
            uint32_t u7 = h4[(size_t)s7 * 64 + lane];
            float w0 = fast_tanh(ad0.x + ar_d) * ad0.y * dinv_d;
            float w1 = fast_tanh(ad1.x + ar_d) * ad1.y * dinv_d;
            float w2 = fast_tanh(ad2.x + ar_d) * ad2.y * dinv_d;
            float w3 = fast_tanh(ad3.x + ar_d) * ad3.y * dinv_d;
            float w4 = fast_tanh(ad4.x + ar_d) * ad4.y * dinv_d;
            float w5 = fast_tanh(ad5.x + ar_d) * ad5.y * dinv_d;
            float w6 = fast_tanh(ad6.x + ar_d) * ad6.y * dinv_d;
            float w7 = fast_tanh(ad7.x + ar_d) * ad7.y * dinv_d;
            accx += w0 * bflo(u0) + w1 * bflo(u1) + w2 * bflo(u2) + w3 * bflo(u3);
            accy += w0 * bfhi(u0) + w1 * bfhi(u1) + w2 * bfhi(u2) + w3 * bfhi(u3);
            accx += w4 * bflo(u4) + w5 * bflo(u5) + w6 * bflo(u6) + w7 * bflo(u7);
            accy += w4 * bfhi(u4) + w5 * bfhi(u5) + w6 * bfhi(u6) + w7 * bfhi(u7);
        }
        for (; c < cnt; ++c) {
            int s = __builtin_amdgcn_readlane(myidx, c);
            float2 ad = AD[s];
            uint32_t u = h4[(size_t)s * 64 + lane];
            float w = fast_tanh(ad.x + ar_d) * ad.y * dinv_d;
            accx += w * bflo(u);
            accy += w * bfhi(u);
        }
    }
    ((uint32_t*)hnb)[(size_t)d * 64 + lane] =
        (uint32_t)f2bf(accx) | ((uint32_t)f2bf(accy) << 16);
    if (attl_next) {
        float al0 = attl_next[2 * lane], al1 = attl_next[2 * lane + 1];
        float ar0 = attr_next[2 * lane], ar1 = attr_next[2 * lane + 1];
        float p = accx * al0 + accy * al1;
        float q = accx * ar0 + accy * ar1;
#pragma unroll
        for (int off = 32; off; off >>= 1) { p += __shfl_xor(p, off); q += __shfl_xor(q, off); }
        if (lane == 0) {
            float2 v; v.x = p; v.y = dinv_d;
            ADout[d] = v;
            ARout[d] = q;
        }
    }
}

// ---- head: emb = h @ W2^T + b2; out0 = log_softmax(emb); out1 = emb ----
// v7 (kept): A-operand exactly bf16; 2-MFMA split on w2 hi/lo.
__global__ __launch_bounds__(256) void head_kernel(const ushort* __restrict__ hb,
                                                   const float* __restrict__ w2,
                                                   const float* __restrict__ b2,
                                                   float* __restrict__ out) {
    __shared__ __attribute__((aligned(16))) ushort bhi_sm[ODIM * HID]; // 16 KB
    __shared__ __attribute__((aligned(16))) ushort blo_sm[ODIM * HID]; // 16 KB
    int t = threadIdx.x;
    int wv = __builtin_amdgcn_readfirstlane(t >> 6);
    int lane = t & 63;

    // ---- stage w2 -> hi/lo bf16, 16B-granule XOR swizzle (key = row&7) ----
    {
        int j = t >> 2;                 // output col 0..63
        int k0 = (t & 3) * 32;          // k chunk
        const float* wr = w2 + (size_t)j * HID + k0;
#pragma unroll
        for (int gg = 0; gg < 4; ++gg) {
            float4 a4 = *(const float4*)(wr + gg * 8);
            float4 b4 = *(const float4*)(wr + gg * 8 + 4);
            float vals[8] = {a4.x, a4.y, a4.z, a4.w, b4.x, b4.y, b4.z, b4.w};
            short8 vhi, vlo;
#pragma unroll
            for (int e = 0; e < 8; ++e) {
                ushort hu = f2bf(vals[e]);
                ushort lu = f2bf(vals[e] - bf2f(hu));
                vhi[e] = (short)hu; vlo[e] = (short)lu;
            }
            int g = (t & 3) * 4 + gg;          // granule 0..15
            int p = g ^ (j & 7);
            *(short8*)&bhi_sm[(size_t)j * HID + p * 8] = vhi;
            *(short8*)&blo_sm[(size_t)j * HID + p * 8] = vlo;
        }
    }
    __syncthreads();

    int rsel = lane & 15;
    int q16 = lane >> 4;            // 0..3
    int koff = q16 * 8;
    int sw = rsel & 7;
    int m0 = blockIdx.x * 128 + wv * 32;   // 32 nodes per wave

    f32x4 acc[2][4];
#pragma unroll
    for (int ms = 0; ms < 2; ++ms)
#pragma unroll
        for (int nt = 0; nt < 4; ++nt) acc[ms][nt] = (f32x4){0.f, 0.f, 0.f, 0.f};

#pragma unroll
    for (int ks = 0; ks < 4; ++ks) {
        short8 a[2];
#pragma unroll
        for (int ms = 0; ms < 2; ++ms) {
            int row = m0 + ms * 16 + rsel; if (row >= NN) row = NN - 1;
            a[ms] = *(const short8*)(hb + (size_t)row * HID + ks * 32 + koff);
        }
        int p = (ks * 4 + q16) ^ sw;
#pragma unroll
        for (int nt = 0; nt < 4; ++nt) {
            size_t bofs = (size_t)(nt * 16 + rsel) * HID + p * 8;
            short8 bh = *(const short8*)&bhi_sm[bofs];
            short8 bl = *(const short8*)&blo_sm[bofs];
#pragma unroll
            for (int ms = 0; ms < 2; ++ms) {
                acc[ms][nt] = __builtin_amdgcn_mfma_f32_16x16x32_bf16(a[ms], bh, acc[ms][nt], 0, 0, 0);
                acc[ms][nt] = __builtin_amdgcn_mfma_f32_16x16x32_bf16(a[ms], bl, acc[ms][nt], 0, 0, 0);
            }
        }
    }

    // ---- epilogue: bias, row-softmax via 16-lane shfl tree, both outputs ----
    int col0 = lane & 15;
    float bias[4];
#pragma unroll
    for (int nt = 0; nt < 4; ++nt) bias[nt] = b2[nt * 16 + col0];
#pragma unroll
    for (int ms = 0; ms < 2; ++ms) {
#pragma unroll
        for (int r = 0; r < 4; ++r) {
            int node = m0 + ms * 16 + q16 * 4 + r;
            float v0 = acc[ms][0][r] + bias[0];
            float v1 = acc[ms][1][r] + bias[1];
            float v2 = acc[ms][2][r] + bias[2];
            float v3 = acc[ms][3][r] + bias[3];
            float m = fmaxf(fmaxf(v0, v1), fmaxf(v2, v3));
#pragma unroll
            for (int off = 8; off; off >>= 1) m = fmaxf(m, __shfl_xor(m, off));
            float s = __expf(v0 - m) + __expf(v1 - m) + __expf(v2 - m) + __expf(v3 - m);
#pragma unroll
            for (int off = 8; off; off >>= 1) s += __shfl_xor(s, off);
            float ls = m + __logf(s);
            if (node < NN) {
                out[(size_t)node * ODIM + 0 * 16 + col0] = v0 - ls;
                out[(size_t)node * ODIM + 1 * 16 + col0] = v1 - ls;
                out[(size_t)node * ODIM + 2 * 16 + col0] = v2 - ls;
                out[(size_t)node * ODIM + 3 * 16 + col0] = v3 - ls;
                size_t eb = (size_t)NN * ODIM + (size_t)node * ODIM;
                out[eb + 0 * 16 + col0] = v0;
                out[eb + 1 * 16 + col0] = v1;
                out[eb + 2 * 16 + col0] = v2;
                out[eb + 3 * 16 + col0] = v3;
            }
        }
    }
}

extern "C" void kernel_launch(void* const* d_in, const int* in_sizes, int n_in,
                              void* d_out, int out_size, void* d_ws, size_t ws_size,
                              hipStream_t stream) {
    const float* x    = (const float*)d_in[0];
    const int*   ei   = (const int*)d_in[1];
    const float* t1w  = (const float*)d_in[2];
    const float* t1b  = (const float*)d_in[3];
    const float* t2w  = (const float*)d_in[4];
    const float* t2b  = (const float*)d_in[5];
    const float* attl = (const float*)d_in[6];
    const float* attr = (const float*)d_in[7];
    float* out = (float*)d_out;

    const int* src = ei;
    const int* dst = ei + NE;

    char* ws = (char*)d_ws;
    size_t off = 0;
    auto alloc = [&](size_t bytes) { char* p = ws + off; off += (bytes + 255) & ~(size_t)255; return p; };
    ushort* h0b  = (ushort*)alloc((size_t)NN * HID * 2);  // bf16 h0 (also raw)
    ushort* h1b  = (ushort*)alloc((size_t)NN * HID * 2);
    ushort* h2b  = (ushort*)alloc((size_t)NN * HID * 2);
    ushort* h3b  = (ushort*)alloc((size_t)NN * HID * 2);
    ushort* wbf  = (ushort*)alloc((size_t)HID * IN_DIM * 2);
    int*    deg  = (int*)alloc((size_t)NN * 4);
    float*  dinv = (float*)alloc((size_t)NN * 4);
    int*    rowptr = (int*)alloc((size_t)(NN + 1) * 4);
    int*    cursor = (int*)alloc((size_t)NN * 4);
    int*    csr_src = (int*)alloc((size_t)NE * 4);
    int*    localScan = (int*)alloc((size_t)NN * 4);
    int*    blockSums = (int*)alloc((size_t)256 * 4);
    int*    blockOff  = (int*)alloc((size_t)256 * 4);
    float2* AD_A = (float2*)alloc((size_t)NN * 8);
    float*  AR_A = (float*)alloc((size_t)NN * 4);
    float2* AD_B = (float2*)alloc((size_t)NN * 8);
    float*  AR_B = (float*)alloc((size_t)NN * 4);
    (void)ws_size;

    hipMemsetAsync(deg, 0, (size_t)NN * 4, stream);

    dim3 blk(256);
    deg_kernel<<<(NE + 255) / 256, blk, 0, stream>>>(dst, deg);
    scanA_kernel<<<NBLK, blk, 0, stream>>>(deg, localScan, blockSums, dinv);
    scanB_kernel<<<1, blk, 0, stream>>>(blockSums, blockOff);
    scanC_kernel<<<NBLK, blk, 0, stream>>>(localScan, blockOff, rowptr, cursor);
    fill_kernel<<<(NE + 255) / 256, blk, 0, stream>>>(src, dst, cursor, csr_src);

    cvtw_kernel<<<(HID * IN_DIM + 255) / 256, blk, 0, stream>>>(t1w, wbf);
    // 196 blocks x 1024 threads, 256 rows each, B staged once per block
    gemm1_kernel<<<(NN + 255) / 256, dim3(1024), 0, stream>>>(x, wbf, t1b,
                                                              attl + 0 * HID, attr + 0 * HID,
                                                              dinv, h0b, AD_A, AR_A);

    // L0: h0b -> h1b (raw = h0b), epilogue computes layer-1 scalars
    agg_kernel<<<(NN + 3) / 4, blk, 0, stream>>>(h0b, h0b, h1b, rowptr, csr_src, dinv,
                                                 AD_A, AR_A, attl + 1 * HID, attr + 1 * HID, AD_B, AR_B);
    // L1: h1b -> h2b
    agg_kernel<<<(NN + 3) / 4, blk, 0, stream>>>(h1b, h0b, h2b, rowptr, csr_src, dinv,
                                                 AD_B, AR_B, attl + 2 * HID, attr + 2 * HID, AD_A, AR_A);
    // L2: h2b -> h3b, no epilogue
    agg_kernel<<<(NN + 3) / 4, blk, 0, stream>>>(h2b, h0b, h3b, rowptr, csr_src, dinv,
                                                 AD_A, AR_A, nullptr, nullptr, nullptr, nullptr);

    // 391 blocks x 256 threads, 128 nodes each (32 per wave)
    head_kernel<<<(NN + 127) / 128, blk, 0, stream>>>(h3b, t2w, t2b, out);
}

// Round 10
// 353.431 us; speedup vs baseline: 1.4601x; 1.0522x over previous
//
#include <hip/hip_runtime.h>
#include <hip/hip_bf16.h>
#include <stdint.h>

#define NN 50000
#define NE 600000
#define IN_DIM 512
#define HID 128
#define ODIM 64
#define EPSV 0.1f
#define NBLK ((NN + 255) / 256)  // 196 scan blocks

typedef __attribute__((ext_vector_type(8))) short short8;
typedef __attribute__((ext_vector_type(4))) float f32x4;

__device__ __forceinline__ ushort f2bf(float f) {
    union { float f; uint32_t i; } v; v.f = f;
    uint32_t lsb = (v.i >> 16) & 1u;
    uint32_t r = v.i + 0x7fffu + lsb;
    return (ushort)(r >> 16);
}

__device__ __forceinline__ float bf2f(ushort u) {
    union { uint32_t i; float f; } v; v.i = ((uint32_t)u) << 16;
    return v.f;
}

// unpack a dword holding 2 bf16 (lo = even col, hi = odd col)
__device__ __forceinline__ float bflo(uint32_t u) {
    union { uint32_t i; float f; } v; v.i = u << 16; return v.f;
}
__device__ __forceinline__ float bfhi(uint32_t u) {
    union { uint32_t i; float f; } v; v.i = u & 0xffff0000u; return v.f;
}

__device__ __forceinline__ short8 pack8(float4 lo, float4 hi) {
    short8 r;
    r[0] = (short)f2bf(lo.x); r[1] = (short)f2bf(lo.y);
    r[2] = (short)f2bf(lo.z); r[3] = (short)f2bf(lo.w);
    r[4] = (short)f2bf(hi.x); r[5] = (short)f2bf(hi.y);
    r[6] = (short)f2bf(hi.z); r[7] = (short)f2bf(hi.w);
    return r;
}

// fast tanh: (e^2z - 1) / (e^2z + 1), clamped
__device__ __forceinline__ float fast_tanh(float z) {
    z = fminf(fmaxf(z, -15.f), 15.f);
    float t = __expf(2.f * z);
    return __fdividef(t - 1.f, t + 1.f);
}

__device__ __forceinline__ float readlane_f(float v, int l) {
    return __int_as_float(__builtin_amdgcn_readlane(__float_as_int(v), l));
}

// ---- degree count ----
__global__ __launch_bounds__(256) void deg_kernel(const int* __restrict__ dst, int* __restrict__ deg) {
    int e = blockIdx.x * 256 + threadIdx.x;
    if (e < NE) atomicAdd(&deg[dst[e]], 1);
}

// ---- scan phase A ----
__global__ __launch_bounds__(256) void scanA_kernel(const int* __restrict__ deg,
                                                    int* __restrict__ localScan,
                                                    int* __restrict__ blockSums,
                                                    float* __restrict__ dinv) {
    __shared__ int tmp[256];
    int t = threadIdx.x;
    int i = blockIdx.x * 256 + t;
    int v = (i < NN) ? deg[i] : 0;
    tmp[t] = v;
    __syncthreads();
    for (int off = 1; off < 256; off <<= 1) {
        int add = (t >= off) ? tmp[t - off] : 0;
        __syncthreads();
        tmp[t] += add;
        __syncthreads();
    }
    if (i < NN) {
        localScan[i] = tmp[t] - v;
        dinv[i] = (v > 0) ? (1.0f / sqrtf((float)v)) : 0.0f;
    }
    if (t == 255) blockSums[blockIdx.x] = tmp[255];
}

// ---- scan phase B ----
__global__ __launch_bounds__(256) void scanB_kernel(const int* __restrict__ blockSums,
                                                    int* __restrict__ blockOff) {
    __shared__ int tmp[256];
    int t = threadIdx.x;
    int v = (t < NBLK) ? blockSums[t] : 0;
    tmp[t] = v;
    __syncthreads();
    for (int off = 1; off < 256; off <<= 1) {
        int add = (t >= off) ? tmp[t - off] : 0;
        __syncthreads();
        tmp[t] += add;
        __syncthreads();
    }
    blockOff[t] = tmp[t] - v;
}

// ---- scan phase C ----
__global__ __launch_bounds__(256) void scanC_kernel(const int* __restrict__ localScan,
                                                    const int* __restrict__ blockOff,
                                                    int* __restrict__ rowptr,
                                                    int* __restrict__ cursor) {
    int i = blockIdx.x * 256 + threadIdx.x;
    if (i < NN) {
        int v = localScan[i] + blockOff[blockIdx.x];
        rowptr[i] = v;
        cursor[i] = v;
    }
    if (i == 0) rowptr[NN] = NE;
}

// ---- fill CSR ----
__global__ __launch_bounds__(256) void fill_kernel(const int* __restrict__ src, const int* __restrict__ dst,
                                                   int* __restrict__ cursor, int* __restrict__ csr_src) {
    int e = blockIdx.x * 256 + threadIdx.x;
    if (e < NE) {
        int d = dst[e];
        int slot = atomicAdd(&cursor[d], 1);
        csr_src[slot] = src[e];
    }
}

// ---- convert W1 fp32 -> bf16 ----
__global__ __launch_bounds__(256) void cvtw_kernel(const float* __restrict__ w, ushort* __restrict__ wbf) {
    int i = blockIdx.x * 256 + threadIdx.x;
    if (i < HID * IN_DIM) wbf[i] = f2bf(w[i]);
}

// ---- h0 = relu(x @ W1^T + b1), fused layer-0 attention scalars ----
// v5 (kept): B staged once per 1024-thread block (B traffic 400 -> 25 MB);
// bf16 h0 out; AD/AR from f32 accumulators.
__global__ __launch_bounds__(1024, 4) void gemm1_kernel(const float* __restrict__ x,
                                                        const ushort* __restrict__ wbf,
                                                        const float* __restrict__ b,
                                                        const float* __restrict__ attl,
                                                        const float* __restrict__ attr,
                                                        const float* __restrict__ dinv,
                                                        ushort* __restrict__ hb,
                                                        float2* __restrict__ AD,
                                                        float* __restrict__ AR) {
    __shared__ __attribute__((aligned(16))) ushort b_sm[HID * IN_DIM]; // 128 KB
    int t = threadIdx.x;
    int wv = __builtin_amdgcn_readfirstlane(t >> 6);   // 0..15
    int lane = t & 63;
    int m0 = blockIdx.x * 256;

    // ---- stage B: 8 rounds x 1024 threads x 16B granule, row-XOR swizzle ----
    {
        uint4 bg[8];
#pragma unroll
        for (int rnd = 0; rnd < 8; ++rnd)
            bg[rnd] = *(const uint4*)(wbf + (size_t)(rnd * 1024 + t) * 8);
#pragma unroll
        for (int rnd = 0; rnd < 8; ++rnd) {
            int G = rnd * 1024 + t;            // global granule 0..8191
            int row = G >> 6;                  // B row 0..127
            int g = G & 63;                    // granule within row
            *(uint4*)&b_sm[(size_t)((row << 6) | (g ^ (row & 7))) * 8] = bg[rnd];
        }
    }
    __syncthreads();

    // fragment map
    int rsel = lane & 15;          // A row within stripe / B row select
    int koff = (lane >> 4) * 8;    // K sub-offset (floats / ushorts)
    int sw = rsel & 7;             // B row swizzle key
    int qg = koff >> 3;            // quarter-granule index 0..3
    int row = m0 + wv * 16 + rsel; if (row >= NN) row = NN - 1;
    const float* xr = x + (size_t)row * IN_DIM + koff;

    f32x4 acc[8];
#pragma unroll
    for (int tt = 0; tt < 8; ++tt) acc[tt] = (f32x4){0.f, 0.f, 0.f, 0.f};

    // depth-2 prefetch: two K-steps (2 x 8 floats/lane) in flight
    float4 c0lo = *(const float4*)(xr);
    float4 c0hi = *(const float4*)(xr + 4);
    float4 c1lo = *(const float4*)(xr + 32);
    float4 c1hi = *(const float4*)(xr + 36);

#pragma unroll
    for (int ks = 0; ks < 16; ks += 2) {
        float4 n0lo, n0hi, n1lo, n1hi;
        bool more = (ks + 2 < 16);
        if (more) {
            n0lo = *(const float4*)(xr + (ks + 2) * 32);
            n0hi = *(const float4*)(xr + (ks + 2) * 32 + 4);
            n1lo = *(const float4*)(xr + (ks + 3) * 32);
            n1hi = *(const float4*)(xr + (ks + 3) * 32 + 4);
        }
        short8 a0 = pack8(c0lo, c0hi);
#pragma unroll
        for (int tt = 0; tt < 8; ++tt) {
            int rb = tt * 16 + rsel;
            short8 bf = *(const short8*)&b_sm[(size_t)(rb << 9) + (size_t)(((ks * 4 + qg) ^ sw) << 3)];
            acc[tt] = __builtin_amdgcn_mfma_f32_16x16x32_bf16(a0, bf, acc[tt], 0, 0, 0);
        }
        short8 a1 = pack8(c1lo, c1hi);
#pragma unroll
        for (int tt = 0; tt < 8; ++tt) {
            int rb = tt * 16 + rsel;
            short8 bf = *(const short8*)&b_sm[(size_t)(rb << 9) + (size_t)((((ks + 1) * 4 + qg) ^ sw) << 3)];
            acc[tt] = __builtin_amdgcn_mfma_f32_16x16x32_bf16(a1, bf, acc[tt], 0, 0, 0);
        }
        if (more) { c0lo = n0lo; c0hi = n0hi; c1lo = n1lo; c1hi = n1hi; }
    }

    // epilogue: bias + relu + bf16 store + fused layer-0 att scalars
    int rbase = (lane >> 4) * 4;
    int col0 = lane & 15;
    float alv[8], arv[8], bias[8];
#pragma unroll
    for (int tt = 0; tt < 8; ++tt) {
        alv[tt]  = attl[tt * 16 + col0];
        arv[tt]  = attr[tt * 16 + col0];
        bias[tt] = b[tt * 16 + col0];
    }
#pragma unroll
    for (int r = 0; r < 4; ++r) {
        int rrow = m0 + wv * 16 + rbase + r;
        float p = 0.f, q = 0.f;
#pragma unroll
        for (int tt = 0; tt < 8; ++tt) {
            float v = acc[tt][r] + bias[tt];
            v = v > 0.f ? v : 0.f;
            if (rrow < NN) hb[(size_t)rrow * HID + tt * 16 + col0] = f2bf(v);
            p += v * alv[tt];
            q += v * arv[tt];
        }
#pragma unroll
        for (int off = 8; off; off >>= 1) { p += __shfl_xor(p, off); q += __shfl_xor(q, off); }
        if (col0 == 0 && rrow < NN) {
            float2 vv; vv.x = p; vv.y = dinv[rrow];
            AD[rrow] = vv;
            AR[rrow] = q;
        }
    }
}

// ---- FAConv aggregation: wave per dst node ----
// v9: per-lane weight precompute. Per 64-edge block: ONE per-lane AD gather
// + ONE tanh pass computes all 64 edge weights (v8 had all 64 lanes
// redundantly evaluating each edge's tanh, 8 per chunk, ON the AD-load
// dependency chain). Weights extracted via readlane (SGPR operand into the
// FMA). Row loads depend only on the idx register -> they issue while the
// tanh pass computes. Per-edge math bit-identical (same formula, inputs,
// accumulation order) -> absmax must stay exactly 0.03125.
__global__ __launch_bounds__(256) void agg_kernel(const ushort* __restrict__ hb,
                                                  const ushort* __restrict__ rawb,
                                                  ushort* __restrict__ hnb,
                                                  const int* __restrict__ rowptr,
                                                  const int* __restrict__ csr_src,
                                                  const float* __restrict__ dinv,
                                                  const float2* __restrict__ AD,
                                                  const float* __restrict__ AR,
                                                  const float* __restrict__ attl_next,
                                                  const float* __restrict__ attr_next,
                                                  float2* __restrict__ ADout,
                                                  float* __restrict__ ARout) {
    int wv = __builtin_amdgcn_readfirstlane(threadIdx.x >> 6);
    int lane = threadIdx.x & 63;
    int d = blockIdx.x * 4 + wv;
    if (d >= NN) return;
    const uint32_t* h4 = (const uint32_t*)hb;   // 2 bf16 per dword, 64 dwords/row
    float ar_d = AR[d];
    float dinv_d = dinv[d];
    uint32_t rawd = ((const uint32_t*)rawb)[(size_t)d * 64 + lane];
    float accx = EPSV * bflo(rawd), accy = EPSV * bfhi(rawd);
    int e0 = rowptr[d], e1 = rowptr[d + 1];
    for (int base = e0; base < e1; base += 64) {
        int cnt = e1 - base; if (cnt > 64) cnt = 64;
        int gi = base + lane; if (gi > NE - 1) gi = NE - 1;
        int myidx = csr_src[gi];               // one load covers 64 edges
        float2 adl = AD[myidx];                // per-lane 8B gather, 64 edges
        float wl = fast_tanh(adl.x + ar_d) * adl.y * dinv_d; // 1 tanh pass / 64 edges
        int c = 0;
        for (; c + 8 <= cnt; c += 8) {
            int s0 = __builtin_amdgcn_readlane(myidx, c + 0);
            int s1 = __builtin_amdgcn_readlane(myidx, c + 1);
            int s2 = __builtin_amdgcn_readlane(myidx, c + 2);
            int s3 = __builtin_amdgcn_readlane(myidx, c + 3);
            int s4 = __builtin_amdgcn_readlane(myidx, c + 4);
            int s5 = __builtin_amdgcn_readlane(myidx, c + 5);
            int s6 = __builtin_amdgcn_readlane(myidx, c + 6);
            int s7 = __builtin_amdgcn_readlane(myidx, c + 7);
            uint32_t u0 = h4[(size_t)s0 * 64 + lane];
            uint32_t u1 = h4[(size_t)s1 * 64 + lane];
            uint32_t u2 = h4[(size_t)s2 * 64 + lane];
            uint32_t u3 = h4[(size_t)s3 * 64 + lane];
            uint32_t u4 = h4[(size_t)s4 * 64 + lane];
            uint32_t u5 = h4[(size_t)s5 * 64 + lane];
            uint32_t u6 = h4[(size_t)s6 * 64 + lane];
            uint32_t u7 = h4[(size_t)s7 * 64 + lane];
            float w0 = readlane_f(wl, c + 0);
            float w1 = readlane_f(wl, c + 1);
            float w2 = readlane_f(wl, c + 2);
            float w3 = readlane_f(wl, c + 3);
            float w4 = readlane_f(wl, c + 4);
            float w5 = readlane_f(wl, c + 5);
            float w6 = readlane_f(wl, c + 6);
            float w7 = readlane_f(wl, c + 7);
            accx += w0 * bflo(u0) + w1 * bflo(u1) + w2 * bflo(u2) + w3 * bflo(u3);
            accy += w0 * bfhi(u0) + w1 * bfhi(u1) + w2 * bfhi(u2) + w3 * bfhi(u3);
            accx += w4 * bflo(u4) + w5 * bflo(u5) + w6 * bflo(u6) + w7 * bflo(u7);
            accy += w4 * bfhi(u4) + w5 * bfhi(u5) + w6 * bfhi(u6) + w7 * bfhi(u7);
        }
        for (; c < cnt; ++c) {
            int s = __builtin_amdgcn_readlane(myidx, c);
            uint32_t u = h4[(size_t)s * 64 + lane];
            float w = readlane_f(wl, c);
            accx += w * bflo(u);
            accy += w * bfhi(u);
        }
    }
    ((uint32_t*)hnb)[(size_t)d * 64 + lane] =
        (uint32_t)f2bf(accx) | ((uint32_t)f2bf(accy) << 16);
    if (attl_next) {
        float al0 = attl_next[2 * lane], al1 = attl_next[2 * lane + 1];
        float ar0 = attr_next[2 * lane], ar1 = attr_next[2 * lane + 1];
        float p = accx * al0 + accy * al1;
        float q = accx * ar0 + accy * ar1;
#pragma unroll
        for (int off = 32; off; off >>= 1) { p += __shfl_xor(p, off); q += __shfl_xor(q, off); }
        if (lane == 0) {
            float2 v; v.x = p; v.y = dinv_d;
            ADout[d] = v;
            ARout[d] = q;
        }
    }
}

// ---- head: emb = h @ W2^T + b2; out0 = log_softmax(emb); out1 = emb ----
// v7 (kept): A-operand exactly bf16; 2-MFMA split on w2 hi/lo.
__global__ __launch_bounds__(256) void head_kernel(const ushort* __restrict__ hb,
                                                   const float* __restrict__ w2,
                                                   const float* __restrict__ b2,
                                                   float* __restrict__ out) {
    __shared__ __attribute__((aligned(16))) ushort bhi_sm[ODIM * HID]; // 16 KB
    __shared__ __attribute__((aligned(16))) ushort blo_sm[ODIM * HID]; // 16 KB
    int t = threadIdx.x;
    int wv = __builtin_amdgcn_readfirstlane(t >> 6);
    int lane = t & 63;

    // ---- stage w2 -> hi/lo bf16, 16B-granule XOR swizzle (key = row&7) ----
    {
        int j = t >> 2;                 // output col 0..63
        int k0 = (t & 3) * 32;          // k chunk
        const float* wr = w2 + (size_t)j * HID + k0;
#pragma unroll
        for (int gg = 0; gg < 4; ++gg) {
            float4 a4 = *(const float4*)(wr + gg * 8);
            float4 b4 = *(const float4*)(wr + gg * 8 + 4);
            float vals[8] = {a4.x, a4.y, a4.z, a4.w, b4.x, b4.y, b4.z, b4.w};
            short8 vhi, vlo;
#pragma unroll
            for (int e = 0; e < 8; ++e) {
                ushort hu = f2bf(vals[e]);
                ushort lu = f2bf(vals[e] - bf2f(hu));
                vhi[e] = (short)hu; vlo[e] = (short)lu;
            }
            int g = (t & 3) * 4 + gg;          // granule 0..15
            int p = g ^ (j & 7);
            *(short8*)&bhi_sm[(size_t)j * HID + p * 8] = vhi;
            *(short8*)&blo_sm[(size_t)j * HID + p * 8] = vlo;
        }
    }
    __syncthreads();

    int rsel = lane & 15;
    int q16 = lane >> 4;            // 0..3
    int koff = q16 * 8;
    int sw = rsel & 7;
    int m0 = blockIdx.x * 128 + wv * 32;   // 32 nodes per wave

    f32x4 acc[2][4];
#pragma unroll
    for (int ms = 0; ms < 2; ++ms)
#pragma unroll
        for (int nt = 0; nt < 4; ++nt) acc[ms][nt] = (f32x4){0.f, 0.f, 0.f, 0.f};

#pragma unroll
    for (int ks = 0; ks < 4; ++ks) {
        short8 a[2];
#pragma unroll
        for (int ms = 0; ms < 2; ++ms) {
            int row = m0 + ms * 16 + rsel; if (row >= NN) row = NN - 1;
            a[ms] = *(const short8*)(hb + (size_t)row * HID + ks * 32 + koff);
        }
        int p = (ks * 4 + q16) ^ sw;
#pragma unroll
        for (int nt = 0; nt < 4; ++nt) {
            size_t bofs = (size_t)(nt * 16 + rsel) * HID + p * 8;
            short8 bh = *(const short8*)&bhi_sm[bofs];
            short8 bl = *(const short8*)&blo_sm[bofs];
#pragma unroll
            for (int ms = 0; ms < 2; ++ms) {
                acc[ms][nt] = __builtin_amdgcn_mfma_f32_16x16x32_bf16(a[ms], bh, acc[ms][nt], 0, 0, 0);
                acc[ms][nt] = __builtin_amdgcn_mfma_f32_16x16x32_bf16(a[ms], bl, acc[ms][nt], 0, 0, 0);
            }
        }
    }

    // ---- epilogue: bias, row-softmax via 16-lane shfl tree, both outputs ----
    int col0 = lane & 15;
    float bias[4];
#pragma unroll
    for (int nt = 0; nt < 4; ++nt) bias[nt] = b2[nt * 16 + col0];
#pragma unroll
    for (int ms = 0; ms < 2; ++ms) {
#pragma unroll
        for (int r = 0; r < 4; ++r) {
            int node = m0 + ms * 16 + q16 * 4 + r;
            float v0 = acc[ms][0][r] + bias[0];
            float v1 = acc[ms][1][r] + bias[1];
            float v2 = acc[ms][2][r] + bias[2];
            float v3 = acc[ms][3][r] + bias[3];
            float m = fmaxf(fmaxf(v0, v1), fmaxf(v2, v3));
#pragma unroll
            for (int off = 8; off; off >>= 1) m = fmaxf(m, __shfl_xor(m, off));
            float s = __expf(v0 - m) + __expf(v1 - m) + __expf(v2 - m) + __expf(v3 - m);
#pragma unroll
            for (int off = 8; off; off >>= 1) s += __shfl_xor(s, off);
            float ls = m + __logf(s);
            if (node < NN) {
                out[(size_t)node * ODIM + 0 * 16 + col0] = v0 - ls;
                out[(size_t)node * ODIM + 1 * 16 + col0] = v1 - ls;
                out[(size_t)node * ODIM + 2 * 16 + col0] = v2 - ls;
                out[(size_t)node * ODIM + 3 * 16 + col0] = v3 - ls;
                size_t eb = (size_t)NN * ODIM + (size_t)node * ODIM;
                out[eb + 0 * 16 + col0] = v0;
                out[eb + 1 * 16 + col0] = v1;
                out[eb + 2 * 16 + col0] = v2;
                out[eb + 3 * 16 + col0] = v3;
            }
        }
    }
}

extern "C" void kernel_launch(void* const* d_in, const int* in_sizes, int n_in,
                              void* d_out, int out_size, void* d_ws, size_t ws_size,
                              hipStream_t stream) {
    const float* x    = (const float*)d_in[0];
    const int*   ei   = (const int*)d_in[1];
    const float* t1w  = (const float*)d_in[2];
    const float* t1b  = (const float*)d_in[3];
    const float* t2w  = (const float*)d_in[4];
    const float* t2b  = (const float*)d_in[5];
    const float* attl = (const float*)d_in[6];
    const float* attr = (const float*)d_in[7];
    float* out = (float*)d_out;

    const int* src = ei;
    const int* dst = ei + NE;

    char* ws = (char*)d_ws;
    size_t off = 0;
    auto alloc = [&](size_t bytes) { char* p = ws + off; off += (bytes + 255) & ~(size_t)255; return p; };
    ushort* h0b  = (ushort*)alloc((size_t)NN * HID * 2);  // bf16 h0 (also raw)
    ushort* h1b  = (ushort*)alloc((size_t)NN * HID * 2);
    ushort* h2b  = (ushort*)alloc((size_t)NN * HID * 2);
    ushort* h3b  = (ushort*)alloc((size_t)NN * HID * 2);
    ushort* wbf  = (ushort*)alloc((size_t)HID * IN_DIM * 2);
    int*    deg  = (int*)alloc((size_t)NN * 4);
    float*  dinv = (float*)alloc((size_t)NN * 4);
    int*    rowptr = (int*)alloc((size_t)(NN + 1) * 4);
    int*    cursor = (int*)alloc((size_t)NN * 4);
    int*    csr_src = (int*)alloc((size_t)NE * 4);
    int*    localScan = (int*)alloc((size_t)NN * 4);
    int*    blockSums = (int*)alloc((size_t)256 * 4);
    int*    blockOff  = (int*)alloc((size_t)256 * 4);
    float2* AD_A = (float2*)alloc((size_t)NN * 8);
    float*  AR_A = (float*)alloc((size_t)NN * 4);
    float2* AD_B = (float2*)alloc((size_t)NN * 8);
    float*  AR_B = (float*)alloc((size_t)NN * 4);
    (void)ws_size;

    hipMemsetAsync(deg, 0, (size_t)NN * 4, stream);

    dim3 blk(256);
    deg_kernel<<<(NE + 255) / 256, blk, 0, stream>>>(dst, deg);
    scanA_kernel<<<NBLK, blk, 0, stream>>>(deg, localScan, blockSums, dinv);
    scanB_kernel<<<1, blk, 0, stream>>>(blockSums, blockOff);
    scanC_kernel<<<NBLK, blk, 0, stream>>>(localScan, blockOff, rowptr, cursor);
    fill_kernel<<<(NE + 255) / 256, blk, 0, stream>>>(src, dst, cursor, csr_src);

    cvtw_kernel<<<(HID * IN_DIM + 255) / 256, blk, 0, stream>>>(t1w, wbf);
    // 196 blocks x 1024 threads, 256 rows each, B staged once per block
    gemm1_kernel<<<(NN + 255) / 256, dim3(1024), 0, stream>>>(x, wbf, t1b,
                                                              attl + 0 * HID, attr + 0 * HID,
                                                              dinv, h0b, AD_A, AR_A);

    // L0: h0b -> h1b (raw = h0b), epilogue computes layer-1 scalars
    agg_kernel<<<(NN + 3) / 4, blk, 0, stream>>>(h0b, h0b, h1b, rowptr, csr_src, dinv,
                                                 AD_A, AR_A, attl + 1 * HID, attr + 1 * HID, AD_B, AR_B);
    // L1: h1b -> h2b
    agg_kernel<<<(NN + 3) / 4, blk, 0, stream>>>(h1b, h0b, h2b, rowptr, csr_src, dinv,
                                                 AD_B, AR_B, attl + 2 * HID, attr + 2 * HID, AD_A, AR_A);
    // L2: h2b -> h3b, no epilogue
    agg_kernel<<<(NN + 3) / 4, blk, 0, stream>>>(h2b, h0b, h3b, rowptr, csr_src, dinv,
                                                 AD_A, AR_A, nullptr, nullptr, nullptr, nullptr);

    // 391 blocks x 256 threads, 128 nodes each (32 per wave)
    head_kernel<<<(NN + 127) / 128, blk, 0, stream>>>(h3b, t2w, t2b, out);
}